// Round 2
// baseline (570.660 us; speedup 1.0000x reference)
//
#include <hip/hip_runtime.h>

#define NN 50000
#define NE 800000
#define NL 200000
#define NB_SCAN 196  // ceil(50000/256)

// ---------------- CSR build ----------------

__global__ void k_count(const int* __restrict__ tgt, int* __restrict__ counts) {
    int e = blockIdx.x * blockDim.x + threadIdx.x;
    if (e < NE) atomicAdd(&counts[tgt[e]], 1);
}

__global__ void k_scan1(const int* __restrict__ counts, int* __restrict__ bsum) {
    int i = blockIdx.x * 256 + threadIdx.x;
    int v = (i < NN) ? counts[i] : 0;
    #pragma unroll
    for (int off = 32; off; off >>= 1) v += __shfl_down(v, off, 64);
    __shared__ int ws4[4];
    int wave = threadIdx.x >> 6, lane = threadIdx.x & 63;
    if (lane == 0) ws4[wave] = v;
    __syncthreads();
    if (threadIdx.x == 0) bsum[blockIdx.x] = ws4[0] + ws4[1] + ws4[2] + ws4[3];
}

__global__ void k_scan2(int* __restrict__ bsum, int nb) {
    __shared__ int s[256];
    int t = threadIdx.x;
    int v = (t < nb) ? bsum[t] : 0;
    s[t] = v;
    __syncthreads();
    for (int off = 1; off < 256; off <<= 1) {
        int a = (t >= off) ? s[t - off] : 0;
        __syncthreads();
        s[t] += a;
        __syncthreads();
    }
    if (t < nb) bsum[t] = s[t] - v;  // exclusive
}

__global__ void k_scan3(const int* __restrict__ counts, const int* __restrict__ boff,
                        int* __restrict__ rowptr, int* __restrict__ cursor) {
    __shared__ int s[256];
    int t = threadIdx.x;
    int i = blockIdx.x * 256 + t;
    int v = (i < NN) ? counts[i] : 0;
    s[t] = v;
    __syncthreads();
    for (int off = 1; off < 256; off <<= 1) {
        int a = (t >= off) ? s[t - off] : 0;
        __syncthreads();
        s[t] += a;
        __syncthreads();
    }
    int excl = s[t] - v + boff[blockIdx.x];
    if (i < NN) { rowptr[i] = excl; cursor[i] = excl; }
    if (i == NN - 1) rowptr[NN] = excl + v;  // == NE
}

__global__ void k_fill(const int* __restrict__ src, const int* __restrict__ tgt,
                       int* __restrict__ cursor, int* __restrict__ csr) {
    int e = blockIdx.x * blockDim.x + threadIdx.x;
    if (e < NE) {
        int p = atomicAdd(&cursor[tgt[e]], 1);
        csr[p] = src[e];
    }
}

// ---------------- CSR gather-mean aggregation ----------------
// out[node] = (sum_{e in row} in[csr[e]][0..D)) / max(deg,1)  (+ add[node] optionally)

template <int D>
__global__ void k_agg(const float* __restrict__ in, int inStride,
                      const float* __restrict__ addp, int addStride,
                      float* __restrict__ out, int outStride,
                      const int* __restrict__ rowptr, const int* __restrict__ csr) {
    int node = blockIdx.x * 4 + (threadIdx.x >> 6);
    int lane = threadIdx.x & 63;
    if (node >= NN) return;
    int r0 = rowptr[node], r1 = rowptr[node + 1];
    float s0 = 0.f, s1 = 0.f;
    for (int e = r0; e < r1; e++) {
        const float* row = in + (size_t)csr[e] * inStride;
        s0 += row[lane];
        if (D == 128) s1 += row[lane + 64];
    }
    float inv = 1.0f / fmaxf((float)(r1 - r0), 1.0f);
    s0 *= inv; s1 *= inv;
    if (addp) {
        s0 += addp[(size_t)node * addStride + lane];
        if (D == 128) s1 += addp[(size_t)node * addStride + lane + 64];
    }
    out[(size_t)node * outStride + lane] = s0;
    if (D == 128) out[(size_t)node * outStride + lane + 64] = s1;
}

// ---------------- fused GEMM ----------------
// KCAT (NCAT=0): out = [inA | inB] @ [W1 ; W2] + bias, optional ReLU.
//   inA stride KA, inB stride K-KA, W rows are 128 wide.
// NCAT=1: out cols 0..63 = inA @ W1 (no bias), cols 64..127 = inA @ W2 + bias.
//   inA stride K, W rows are 64 wide.
// out stride 128 always. Tile: 128 nodes x 128 cols per 256-thread block, 8x8 micro-tile.

template <int K, int KA, int NCAT, int RELU>
__global__ void k_gemm(const float* __restrict__ inA, const float* __restrict__ inB,
                       const float* __restrict__ W1, const float* __restrict__ W2,
                       const float* __restrict__ bias, float* __restrict__ out) {
    constexpr int KB = K - KA;
    constexpr int KC = 32;
    __shared__ float sIn[KC][132];  // transposed input tile, padded
    __shared__ float sW[KC][128];

    int tid = threadIdx.x;
    int tx = tid & 15, ty = tid >> 4;
    int bn = blockIdx.x * 128;

    float acc[8][8];
    #pragma unroll
    for (int i = 0; i < 8; i++)
        #pragma unroll
        for (int j = 0; j < 8; j++) acc[i][j] = 0.f;

    int ln = tid >> 1;           // node 0..127 within tile
    int lk = (tid & 1) * 16;     // k offset 0 or 16
    int gn = min(bn + ln, NN - 1);
    int wk = tid >> 3;           // 0..31
    int wc = (tid & 7) * 16;     // 0..112

    for (int k0 = 0; k0 < K; k0 += KC) {
        // stage input (transposed)
        #pragma unroll
        for (int i = 0; i < 4; i++) {
            int kg = k0 + lk + i * 4;
            float4 v;
            if constexpr (NCAT) {
                v = *(const float4*)&inA[(size_t)gn * K + kg];
            } else {
                if (kg < KA) v = *(const float4*)&inA[(size_t)gn * KA + kg];
                else         v = *(const float4*)&inB[(size_t)gn * KB + (kg - KA)];
            }
            int kl = lk + i * 4;
            sIn[kl + 0][ln] = v.x;
            sIn[kl + 1][ln] = v.y;
            sIn[kl + 2][ln] = v.z;
            sIn[kl + 3][ln] = v.w;
        }
        // stage weights
        #pragma unroll
        for (int i = 0; i < 4; i++) {
            int c = wc + i * 4;
            int kg = k0 + wk;
            float4 w;
            if constexpr (NCAT) {
                if (c < 64) w = *(const float4*)&W1[(size_t)kg * 64 + c];
                else        w = *(const float4*)&W2[(size_t)kg * 64 + (c - 64)];
            } else {
                if (kg < KA) w = *(const float4*)&W1[(size_t)kg * 128 + c];
                else         w = *(const float4*)&W2[(size_t)(kg - KA) * 128 + c];
            }
            *(float4*)&sW[wk][c] = w;
        }
        __syncthreads();

        #pragma unroll
        for (int kk = 0; kk < KC; kk++) {
            float4 a0 = *(float4*)&sIn[kk][ty * 8];
            float4 a1 = *(float4*)&sIn[kk][ty * 8 + 4];
            float4 w0 = *(float4*)&sW[kk][tx * 8];
            float4 w1 = *(float4*)&sW[kk][tx * 8 + 4];
            float a[8] = {a0.x, a0.y, a0.z, a0.w, a1.x, a1.y, a1.z, a1.w};
            float w[8] = {w0.x, w0.y, w0.z, w0.w, w1.x, w1.y, w1.z, w1.w};
            #pragma unroll
            for (int i = 0; i < 8; i++)
                #pragma unroll
                for (int j = 0; j < 8; j++) acc[i][j] += a[i] * w[j];
        }
        __syncthreads();
    }

    // epilogue: bias (+ReLU) and store
    float bc[8];
    #pragma unroll
    for (int j = 0; j < 8; j++) {
        int c = tx * 8 + j;
        if constexpr (NCAT) bc[j] = (c < 64) ? 0.f : bias[c - 64];
        else bc[j] = bias[c];
    }
    #pragma unroll
    for (int i = 0; i < 8; i++) {
        int n = bn + ty * 8 + i;
        if (n < NN) {
            float o[8];
            #pragma unroll
            for (int j = 0; j < 8; j++) {
                float v = acc[i][j] + bc[j];
                o[j] = RELU ? fmaxf(v, 0.f) : v;
            }
            *(float4*)&out[(size_t)n * 128 + tx * 8]     = make_float4(o[0], o[1], o[2], o[3]);
            *(float4*)&out[(size_t)n * 128 + tx * 8 + 4] = make_float4(o[4], o[5], o[6], o[7]);
        }
    }
}

// ---------------- decode ----------------

__global__ void k_decode(const int* __restrict__ eli, const float* __restrict__ z,
                         float* __restrict__ out) {
    int w = (blockIdx.x * 256 + threadIdx.x) >> 6;
    int lane = threadIdx.x & 63;
    if (w >= NL) return;
    int a = eli[w], b = eli[NL + w];
    float v = z[(size_t)a * 64 + lane] * z[(size_t)b * 64 + lane];
    #pragma unroll
    for (int off = 32; off; off >>= 1) v += __shfl_xor(v, off, 64);
    if (lane == 0) out[w] = v;
}

// ---------------- launch ----------------

extern "C" void kernel_launch(void* const* d_in, const int* in_sizes, int n_in,
                              void* d_out, int out_size, void* d_ws, size_t ws_size,
                              hipStream_t stream) {
    const float* x   = (const float*)d_in[0];
    const int*   edge = (const int*)d_in[1];   // [2, NE]
    const int*   eli  = (const int*)d_in[2];   // [2, NL]
    const float* Wl1 = (const float*)d_in[3];
    const float* Wr1 = (const float*)d_in[4];
    const float* b1  = (const float*)d_in[5];
    const float* Wl2 = (const float*)d_in[6];
    const float* Wr2 = (const float*)d_in[7];
    const float* b2  = (const float*)d_in[8];
    const float* Wl3 = (const float*)d_in[9];
    const float* Wr3 = (const float*)d_in[10];
    const float* b3  = (const float*)d_in[11];
    float* out = (float*)d_out;

    // workspace carve (256B aligned)
    char* w = (char*)d_ws;
    auto carve = [&](size_t bytes) {
        char* p = w;
        w += (bytes + 255) & ~(size_t)255;
        return p;
    };
    int*   rowptr = (int*)carve((NN + 1) * sizeof(int));
    int*   cursor = (int*)carve(NN * sizeof(int));        // doubles as counts
    int*   csr    = (int*)carve(NE * sizeof(int));
    int*   bsum   = (int*)carve(256 * sizeof(int));
    float* M      = (float*)carve((size_t)NN * 64 * sizeof(float));   // mean1, later z
    float* A      = (float*)carve((size_t)NN * 128 * sizeof(float));  // h1
    float* B      = (float*)carve((size_t)NN * 128 * sizeof(float));  // mean2, later pq
    float* C      = (float*)carve((size_t)NN * 128 * sizeof(float));  // h2

    const int* src = edge;
    const int* tgt = edge + NE;

    hipMemsetAsync(cursor, 0, NN * sizeof(int), stream);
    k_count<<<(NE + 255) / 256, 256, 0, stream>>>(tgt, cursor);
    k_scan1<<<NB_SCAN, 256, 0, stream>>>(cursor, bsum);
    k_scan2<<<1, 256, 0, stream>>>(bsum, NB_SCAN);
    k_scan3<<<NB_SCAN, 256, 0, stream>>>(cursor, bsum, rowptr, cursor);
    k_fill<<<(NE + 255) / 256, 256, 0, stream>>>(src, tgt, cursor, csr);

    // layer 1: mean1 = mean(x); h1 = relu([mean1|x] @ [Wl1;Wr1] + b1)
    k_agg<64><<<(NN + 3) / 4, 256, 0, stream>>>(x, 64, nullptr, 0, M, 64, rowptr, csr);
    k_gemm<128, 64, 0, 1><<<(NN + 127) / 128, 256, 0, stream>>>(M, x, Wl1, Wr1, b1, A);

    // layer 2: mean2 = mean(h1); h2 = relu([mean2|h1] @ [Wl2;Wr2] + b2)
    k_agg<128><<<(NN + 3) / 4, 256, 0, stream>>>(A, 128, nullptr, 0, B, 128, rowptr, csr);
    k_gemm<256, 128, 0, 1><<<(NN + 127) / 128, 256, 0, stream>>>(B, A, Wl2, Wr2, b2, C);

    // layer 3 (GEMM first, then scatter 64-wide): pq = h2 @ [Wl3 | Wr3]; q gets b3
    k_gemm<128, 128, 1, 0><<<(NN + 127) / 128, 256, 0, stream>>>(C, nullptr, Wl3, Wr3, b3, B);
    // z = scatter_mean(p) + q
    k_agg<64><<<(NN + 3) / 4, 256, 0, stream>>>(B, 128, B + 64, 128, M, 64, rowptr, csr);

    // decode: out[l] = dot(z[a], z[b])
    k_decode<<<(NL * 64 + 255) / 256, 256, 0, stream>>>(eli, M, out);
}

// Round 4
// 491.444 us; speedup vs baseline: 1.1612x; 1.1612x over previous
//
#include <hip/hip_runtime.h>

#define NN 50000
#define NE 800000
#define NL 200000
#define NB_SCAN 196  // ceil(50000/256)

// ---------------- CSR build ----------------

__global__ void k_count(const int* __restrict__ tgt, int* __restrict__ counts) {
    int e = blockIdx.x * blockDim.x + threadIdx.x;
    if (e < NE) atomicAdd(&counts[tgt[e]], 1);
}

__global__ void k_scan1(const int* __restrict__ counts, int* __restrict__ bsum) {
    int i = blockIdx.x * 256 + threadIdx.x;
    int v = (i < NN) ? counts[i] : 0;
    #pragma unroll
    for (int off = 32; off; off >>= 1) v += __shfl_down(v, off, 64);
    __shared__ int ws4[4];
    int wave = threadIdx.x >> 6, lane = threadIdx.x & 63;
    if (lane == 0) ws4[wave] = v;
    __syncthreads();
    if (threadIdx.x == 0) bsum[blockIdx.x] = ws4[0] + ws4[1] + ws4[2] + ws4[3];
}

__global__ void k_scan2(int* __restrict__ bsum, int nb) {
    __shared__ int s[256];
    int t = threadIdx.x;
    int v = (t < nb) ? bsum[t] : 0;
    s[t] = v;
    __syncthreads();
    for (int off = 1; off < 256; off <<= 1) {
        int a = (t >= off) ? s[t - off] : 0;
        __syncthreads();
        s[t] += a;
        __syncthreads();
    }
    if (t < nb) bsum[t] = s[t] - v;  // exclusive
}

__global__ void k_scan3(const int* __restrict__ counts, const int* __restrict__ boff,
                        int* __restrict__ rowptr, int* __restrict__ cursor) {
    __shared__ int s[256];
    int t = threadIdx.x;
    int i = blockIdx.x * 256 + t;
    int v = (i < NN) ? counts[i] : 0;
    s[t] = v;
    __syncthreads();
    for (int off = 1; off < 256; off <<= 1) {
        int a = (t >= off) ? s[t - off] : 0;
        __syncthreads();
        s[t] += a;
        __syncthreads();
    }
    int excl = s[t] - v + boff[blockIdx.x];
    if (i < NN) { rowptr[i] = excl; cursor[i] = excl; }
    if (i == NN - 1) rowptr[NN] = excl + v;  // == NE
}

__global__ void k_fill(const int* __restrict__ src, const int* __restrict__ tgt,
                       int* __restrict__ cursor, int* __restrict__ csr) {
    int e = blockIdx.x * blockDim.x + threadIdx.x;
    if (e < NE) {
        int p = atomicAdd(&cursor[tgt[e]], 1);
        csr[p] = src[e];
    }
}

// ---------------- CSR gather-mean aggregation ----------------

template <int D>
__global__ void k_agg(const float* __restrict__ in, int inStride,
                      const float* __restrict__ addp, int addStride,
                      float* __restrict__ out, int outStride,
                      const int* __restrict__ rowptr, const int* __restrict__ csr) {
    int node = blockIdx.x * 4 + (threadIdx.x >> 6);
    int lane = threadIdx.x & 63;
    if (node >= NN) return;
    int r0 = rowptr[node], r1 = rowptr[node + 1];
    float s0 = 0.f, s1 = 0.f;
    for (int e = r0; e < r1; e++) {
        const float* row = in + (size_t)csr[e] * inStride;
        s0 += row[lane];
        if (D == 128) s1 += row[lane + 64];
    }
    float inv = 1.0f / fmaxf((float)(r1 - r0), 1.0f);
    s0 *= inv; s1 *= inv;
    if (addp) {
        s0 += addp[(size_t)node * addStride + lane];
        if (D == 128) s1 += addp[(size_t)node * addStride + lane + 64];
    }
    out[(size_t)node * outStride + lane] = s0;
    if (D == 128) out[(size_t)node * outStride + lane + 64] = s1;
}

// ---------------- fused GEMM ----------------
// Tile: 64 nodes x 128 cols per 256-thread block (782 blocks -> ~3 blocks/CU).
// Micro-tile 4 rows x 8 cols, cols split as {tx*4, 64+tx*4} so the hot-loop
// ds_read_b128 of weights is 2-way bank-aliased (free) instead of 4-way.
// KCAT (NCAT=0): out = [inA | inB] @ [W1 ; W2] + bias, optional ReLU.
// NCAT=1: out cols 0..63 = inA @ W1 (no bias), cols 64..127 = inA @ W2 + bias.

template <int K, int KA, int NCAT, int RELU>
__global__ void k_gemm(const float* __restrict__ inA, const float* __restrict__ inB,
                       const float* __restrict__ W1, const float* __restrict__ W2,
                       const float* __restrict__ bias, float* __restrict__ out) {
    constexpr int KB = K - KA;
    constexpr int KC = 32;
    __shared__ float sIn[KC][66];    // transposed input tile [k][node], padded
    __shared__ float sW[KC][132];    // weight tile [k][col], padded

    int tid = threadIdx.x;
    int tx = tid & 15;               // col group: cols {tx*4..+3} and {64+tx*4..+3}
    int ty = tid >> 4;               // row group: rows ty*4..ty*4+3
    int bn = blockIdx.x * 64;

    float acc[4][8];
    #pragma unroll
    for (int i = 0; i < 4; i++)
        #pragma unroll
        for (int j = 0; j < 8; j++) acc[i][j] = 0.f;

    int ln = tid >> 2;               // node 0..63 within tile
    int lk = (tid & 3) * 8;          // k offset 0,8,16,24
    int gn = min(bn + ln, NN - 1);
    int wk = tid >> 3;               // 0..31
    int wc = (tid & 7) * 16;         // 0..112

    for (int k0 = 0; k0 < K; k0 += KC) {
        // stage input (transposed): each thread 8 floats (2 float4)
        {
            float4 v0, v1;
            int kg = k0 + lk;
            if constexpr (NCAT) {
                v0 = *(const float4*)&inA[(size_t)gn * K + kg];
                v1 = *(const float4*)&inA[(size_t)gn * K + kg + 4];
            } else {
                if (kg < KA) v0 = *(const float4*)&inA[(size_t)gn * KA + kg];
                else         v0 = *(const float4*)&inB[(size_t)gn * KB + (kg - KA)];
                if (kg + 4 < KA) v1 = *(const float4*)&inA[(size_t)gn * KA + kg + 4];
                else             v1 = *(const float4*)&inB[(size_t)gn * KB + (kg + 4 - KA)];
            }
            sIn[lk + 0][ln] = v0.x; sIn[lk + 1][ln] = v0.y;
            sIn[lk + 2][ln] = v0.z; sIn[lk + 3][ln] = v0.w;
            sIn[lk + 4][ln] = v1.x; sIn[lk + 5][ln] = v1.y;
            sIn[lk + 6][ln] = v1.z; sIn[lk + 7][ln] = v1.w;
        }
        // stage weights: each thread 16 floats (4 float4)
        #pragma unroll
        for (int i = 0; i < 4; i++) {
            int c = wc + i * 4;
            int kg = k0 + wk;
            float4 w;
            if constexpr (NCAT) {
                if (c < 64) w = *(const float4*)&W1[(size_t)kg * 64 + c];
                else        w = *(const float4*)&W2[(size_t)kg * 64 + (c - 64)];
            } else {
                if (kg < KA) w = *(const float4*)&W1[(size_t)kg * 128 + c];
                else         w = *(const float4*)&W2[(size_t)(kg - KA) * 128 + c];
            }
            *(float4*)&sW[wk][c] = w;
        }
        __syncthreads();

        #pragma unroll
        for (int kk = 0; kk < KC; kk++) {
            float4 av = *(float4*)&sIn[kk][ty * 4];
            float4 w0 = *(float4*)&sW[kk][tx * 4];
            float4 w1 = *(float4*)&sW[kk][64 + tx * 4];
            float a[4] = {av.x, av.y, av.z, av.w};
            float w[8] = {w0.x, w0.y, w0.z, w0.w, w1.x, w1.y, w1.z, w1.w};
            #pragma unroll
            for (int i = 0; i < 4; i++)
                #pragma unroll
                for (int j = 0; j < 8; j++) acc[i][j] += a[i] * w[j];
        }
        __syncthreads();
    }

    // epilogue: bias (+ReLU) and store
    float bc[8];
    #pragma unroll
    for (int j = 0; j < 8; j++) {
        int c = (j < 4) ? (tx * 4 + j) : (64 + tx * 4 + (j - 4));
        if constexpr (NCAT) bc[j] = (c < 64) ? 0.f : bias[c - 64];
        else bc[j] = bias[c];
    }
    #pragma unroll
    for (int i = 0; i < 4; i++) {
        int n = bn + ty * 4 + i;
        if (n < NN) {
            float o[8];
            #pragma unroll
            for (int j = 0; j < 8; j++) {
                float v = acc[i][j] + bc[j];
                o[j] = RELU ? fmaxf(v, 0.f) : v;
            }
            *(float4*)&out[(size_t)n * 128 + tx * 4]      = make_float4(o[0], o[1], o[2], o[3]);
            *(float4*)&out[(size_t)n * 128 + 64 + tx * 4] = make_float4(o[4], o[5], o[6], o[7]);
        }
    }
}

// ---------------- decode ----------------

__global__ void k_decode(const int* __restrict__ eli, const float* __restrict__ z,
                         float* __restrict__ out) {
    int w = (blockIdx.x * 256 + threadIdx.x) >> 6;
    int lane = threadIdx.x & 63;
    if (w >= NL) return;
    int a = eli[w], b = eli[NL + w];
    float v = z[(size_t)a * 64 + lane] * z[(size_t)b * 64 + lane];
    #pragma unroll
    for (int off = 32; off; off >>= 1) v += __shfl_xor(v, off, 64);
    if (lane == 0) out[w] = v;
}

// ---------------- launch ----------------

extern "C" void kernel_launch(void* const* d_in, const int* in_sizes, int n_in,
                              void* d_out, int out_size, void* d_ws, size_t ws_size,
                              hipStream_t stream) {
    const float* x   = (const float*)d_in[0];
    const int*   edge = (const int*)d_in[1];   // [2, NE]
    const int*   eli  = (const int*)d_in[2];   // [2, NL]
    const float* Wl1 = (const float*)d_in[3];
    const float* Wr1 = (const float*)d_in[4];
    const float* b1  = (const float*)d_in[5];
    const float* Wl2 = (const float*)d_in[6];
    const float* Wr2 = (const float*)d_in[7];
    const float* b2  = (const float*)d_in[8];
    const float* Wl3 = (const float*)d_in[9];
    const float* Wr3 = (const float*)d_in[10];
    const float* b3  = (const float*)d_in[11];
    float* out = (float*)d_out;

    char* w = (char*)d_ws;
    auto carve = [&](size_t bytes) {
        char* p = w;
        w += (bytes + 255) & ~(size_t)255;
        return p;
    };
    int*   rowptr = (int*)carve((NN + 1) * sizeof(int));
    int*   cursor = (int*)carve(NN * sizeof(int));        // doubles as counts
    int*   csr    = (int*)carve(NE * sizeof(int));
    int*   bsum   = (int*)carve(256 * sizeof(int));
    float* M      = (float*)carve((size_t)NN * 64 * sizeof(float));   // mean1, later z
    float* A      = (float*)carve((size_t)NN * 128 * sizeof(float));  // h1
    float* B      = (float*)carve((size_t)NN * 128 * sizeof(float));  // mean2, later pq
    float* C      = (float*)carve((size_t)NN * 128 * sizeof(float));  // h2

    const int* src = edge;
    const int* tgt = edge + NE;

    hipMemsetAsync(cursor, 0, NN * sizeof(int), stream);
    k_count<<<(NE + 255) / 256, 256, 0, stream>>>(tgt, cursor);
    k_scan1<<<NB_SCAN, 256, 0, stream>>>(cursor, bsum);
    k_scan2<<<1, 256, 0, stream>>>(bsum, NB_SCAN);
    k_scan3<<<NB_SCAN, 256, 0, stream>>>(cursor, bsum, rowptr, cursor);
    k_fill<<<(NE + 255) / 256, 256, 0, stream>>>(src, tgt, cursor, csr);

    // layer 1: mean1 = mean(x); h1 = relu([mean1|x] @ [Wl1;Wr1] + b1)
    k_agg<64><<<(NN + 3) / 4, 256, 0, stream>>>(x, 64, nullptr, 0, M, 64, rowptr, csr);
    k_gemm<128, 64, 0, 1><<<(NN + 63) / 64, 256, 0, stream>>>(M, x, Wl1, Wr1, b1, A);

    // layer 2: mean2 = mean(h1); h2 = relu([mean2|h1] @ [Wl2;Wr2] + b2)
    k_agg<128><<<(NN + 3) / 4, 256, 0, stream>>>(A, 128, nullptr, 0, B, 128, rowptr, csr);
    k_gemm<256, 128, 0, 1><<<(NN + 63) / 64, 256, 0, stream>>>(B, A, Wl2, Wr2, b2, C);

    // layer 3 (GEMM first, then scatter 64-wide): pq = h2 @ [Wl3 | Wr3]; q gets b3
    k_gemm<128, 128, 1, 0><<<(NN + 63) / 64, 256, 0, stream>>>(C, nullptr, Wl3, Wr3, b3, B);
    // z = scatter_mean(p) + q
    k_agg<64><<<(NN + 3) / 4, 256, 0, stream>>>(B, 128, B + 64, 128, M, 64, rowptr, csr);

    // decode: out[l] = dot(z[a], z[b])
    k_decode<<<(NL * 64 + 255) / 256, 256, 0, stream>>>(eli, M, out);
}

// Round 5
// 362.599 us; speedup vs baseline: 1.5738x; 1.3553x over previous
//
#include <hip/hip_runtime.h>

#define NN 50000
#define NE 800000
#define NL 200000
#define NB_SCAN 196  // ceil(50000/256)

// ---------------- CSR build ----------------

__global__ void k_count(const int* __restrict__ tgt, int* __restrict__ counts) {
    int e = blockIdx.x * blockDim.x + threadIdx.x;
    if (e < NE) atomicAdd(&counts[tgt[e]], 1);
}

__global__ void k_scan1(const int* __restrict__ counts, int* __restrict__ bsum) {
    int i = blockIdx.x * 256 + threadIdx.x;
    int v = (i < NN) ? counts[i] : 0;
    #pragma unroll
    for (int off = 32; off; off >>= 1) v += __shfl_down(v, off, 64);
    __shared__ int ws4[4];
    int wave = threadIdx.x >> 6, lane = threadIdx.x & 63;
    if (lane == 0) ws4[wave] = v;
    __syncthreads();
    if (threadIdx.x == 0) bsum[blockIdx.x] = ws4[0] + ws4[1] + ws4[2] + ws4[3];
}

__global__ void k_scan2(int* __restrict__ bsum, int nb) {
    __shared__ int s[256];
    int t = threadIdx.x;
    int v = (t < nb) ? bsum[t] : 0;
    s[t] = v;
    __syncthreads();
    for (int off = 1; off < 256; off <<= 1) {
        int a = (t >= off) ? s[t - off] : 0;
        __syncthreads();
        s[t] += a;
        __syncthreads();
    }
    if (t < nb) bsum[t] = s[t] - v;  // exclusive
}

__global__ void k_scan3(const int* __restrict__ counts, const int* __restrict__ boff,
                        int* __restrict__ rowptr, int* __restrict__ cursor) {
    __shared__ int s[256];
    int t = threadIdx.x;
    int i = blockIdx.x * 256 + t;
    int v = (i < NN) ? counts[i] : 0;
    s[t] = v;
    __syncthreads();
    for (int off = 1; off < 256; off <<= 1) {
        int a = (t >= off) ? s[t - off] : 0;
        __syncthreads();
        s[t] += a;
        __syncthreads();
    }
    int excl = s[t] - v + boff[blockIdx.x];
    if (i < NN) { rowptr[i] = excl; cursor[i] = excl; }
    if (i == NN - 1) rowptr[NN] = excl + v;  // == NE
}

__global__ void k_fill(const int* __restrict__ src, const int* __restrict__ tgt,
                       int* __restrict__ cursor, int* __restrict__ csr) {
    int e = blockIdx.x * blockDim.x + threadIdx.x;
    if (e < NE) {
        int p = atomicAdd(&cursor[tgt[e]], 1);
        csr[p] = src[e];
    }
}

// ---------------- CSR gather-mean aggregation ----------------
// One wave per node. Lanes split into EPW edge-slots of LPR lanes; each lane
// loads a float4, so a wave gathers EPW neighbor rows concurrently (vs 1 in
// the scalar version). csr index for the next iteration is prefetched to
// break the index-load -> gather dependency chain.

template <int D>
__global__ void k_agg(const float* __restrict__ in, int inStride,
                      const float* __restrict__ addp, int addStride,
                      float* __restrict__ out, int outStride,
                      const int* __restrict__ rowptr, const int* __restrict__ csr) {
    constexpr int LPR = D / 4;      // lanes per row: 16 (D=64) or 32 (D=128)
    constexpr int EPW = 64 / LPR;   // edges in flight per wave: 4 or 2
    int node = blockIdx.x * 4 + (threadIdx.x >> 6);
    int lane = threadIdx.x & 63;
    if (node >= NN) return;
    int sub = lane / LPR;           // edge slot
    int li  = lane % LPR;           // float4 index within row
    int r0 = rowptr[node], r1 = rowptr[node + 1];

    float4 acc = make_float4(0.f, 0.f, 0.f, 0.f);
    int e = r0 + sub;
    int idx = (e < r1) ? csr[e] : 0;
    while (e < r1) {
        int en = e + EPW;
        int idxn = (en < r1) ? csr[en] : 0;   // prefetch next index
        float4 v = ((const float4*)(in + (size_t)idx * inStride))[li];
        acc.x += v.x; acc.y += v.y; acc.z += v.z; acc.w += v.w;
        e = en; idx = idxn;
    }
    // reduce across edge slots (lanes sharing li)
    #pragma unroll
    for (int off = LPR; off < 64; off <<= 1) {
        acc.x += __shfl_xor(acc.x, off, 64);
        acc.y += __shfl_xor(acc.y, off, 64);
        acc.z += __shfl_xor(acc.z, off, 64);
        acc.w += __shfl_xor(acc.w, off, 64);
    }
    if (sub == 0) {
        float inv = 1.0f / fmaxf((float)(r1 - r0), 1.0f);
        acc.x *= inv; acc.y *= inv; acc.z *= inv; acc.w *= inv;
        if (addp) {
            float4 a = *(const float4*)&addp[(size_t)node * addStride + li * 4];
            acc.x += a.x; acc.y += a.y; acc.z += a.z; acc.w += a.w;
        }
        *(float4*)&out[(size_t)node * outStride + li * 4] = acc;
    }
}

// ---------------- fused GEMM ----------------
// Tile: 64 nodes x 128 cols per 256-thread block (782 blocks -> ~3 blocks/CU).
// Micro-tile 4 rows x 8 cols, cols split as {tx*4, 64+tx*4} so the hot-loop
// ds_read_b128 of weights is 2-way bank-aliased (free) instead of 4-way.
// KCAT (NCAT=0): out = [inA | inB] @ [W1 ; W2] + bias, optional ReLU.
// NCAT=1: out cols 0..63 = inA @ W1 (no bias), cols 64..127 = inA @ W2 + bias.

template <int K, int KA, int NCAT, int RELU>
__global__ void k_gemm(const float* __restrict__ inA, const float* __restrict__ inB,
                       const float* __restrict__ W1, const float* __restrict__ W2,
                       const float* __restrict__ bias, float* __restrict__ out) {
    constexpr int KB = K - KA;
    constexpr int KC = 32;
    __shared__ float sIn[KC][66];    // transposed input tile [k][node], padded
    __shared__ float sW[KC][132];    // weight tile [k][col], padded

    int tid = threadIdx.x;
    int tx = tid & 15;               // col group: cols {tx*4..+3} and {64+tx*4..+3}
    int ty = tid >> 4;               // row group: rows ty*4..ty*4+3
    int bn = blockIdx.x * 64;

    float acc[4][8];
    #pragma unroll
    for (int i = 0; i < 4; i++)
        #pragma unroll
        for (int j = 0; j < 8; j++) acc[i][j] = 0.f;

    int ln = tid >> 2;               // node 0..63 within tile
    int lk = (tid & 3) * 8;          // k offset 0,8,16,24
    int gn = min(bn + ln, NN - 1);
    int wk = tid >> 3;               // 0..31
    int wc = (tid & 7) * 16;         // 0..112

    for (int k0 = 0; k0 < K; k0 += KC) {
        // stage input (transposed): each thread 8 floats (2 float4)
        {
            float4 v0, v1;
            int kg = k0 + lk;
            if constexpr (NCAT) {
                v0 = *(const float4*)&inA[(size_t)gn * K + kg];
                v1 = *(const float4*)&inA[(size_t)gn * K + kg + 4];
            } else {
                if (kg < KA) v0 = *(const float4*)&inA[(size_t)gn * KA + kg];
                else         v0 = *(const float4*)&inB[(size_t)gn * KB + (kg - KA)];
                if (kg + 4 < KA) v1 = *(const float4*)&inA[(size_t)gn * KA + kg + 4];
                else             v1 = *(const float4*)&inB[(size_t)gn * KB + (kg + 4 - KA)];
            }
            sIn[lk + 0][ln] = v0.x; sIn[lk + 1][ln] = v0.y;
            sIn[lk + 2][ln] = v0.z; sIn[lk + 3][ln] = v0.w;
            sIn[lk + 4][ln] = v1.x; sIn[lk + 5][ln] = v1.y;
            sIn[lk + 6][ln] = v1.z; sIn[lk + 7][ln] = v1.w;
        }
        // stage weights: each thread 16 floats (4 float4)
        #pragma unroll
        for (int i = 0; i < 4; i++) {
            int c = wc + i * 4;
            int kg = k0 + wk;
            float4 w;
            if constexpr (NCAT) {
                if (c < 64) w = *(const float4*)&W1[(size_t)kg * 64 + c];
                else        w = *(const float4*)&W2[(size_t)kg * 64 + (c - 64)];
            } else {
                if (kg < KA) w = *(const float4*)&W1[(size_t)kg * 128 + c];
                else         w = *(const float4*)&W2[(size_t)(kg - KA) * 128 + c];
            }
            *(float4*)&sW[wk][c] = w;
        }
        __syncthreads();

        #pragma unroll
        for (int kk = 0; kk < KC; kk++) {
            float4 av = *(float4*)&sIn[kk][ty * 4];
            float4 w0 = *(float4*)&sW[kk][tx * 4];
            float4 w1 = *(float4*)&sW[kk][64 + tx * 4];
            float a[4] = {av.x, av.y, av.z, av.w};
            float w[8] = {w0.x, w0.y, w0.z, w0.w, w1.x, w1.y, w1.z, w1.w};
            #pragma unroll
            for (int i = 0; i < 4; i++)
                #pragma unroll
                for (int j = 0; j < 8; j++) acc[i][j] += a[i] * w[j];
        }
        __syncthreads();
    }

    // epilogue: bias (+ReLU) and store
    float bc[8];
    #pragma unroll
    for (int j = 0; j < 8; j++) {
        int c = (j < 4) ? (tx * 4 + j) : (64 + tx * 4 + (j - 4));
        if constexpr (NCAT) bc[j] = (c < 64) ? 0.f : bias[c - 64];
        else bc[j] = bias[c];
    }
    #pragma unroll
    for (int i = 0; i < 4; i++) {
        int n = bn + ty * 4 + i;
        if (n < NN) {
            float o[8];
            #pragma unroll
            for (int j = 0; j < 8; j++) {
                float v = acc[i][j] + bc[j];
                o[j] = RELU ? fmaxf(v, 0.f) : v;
            }
            *(float4*)&out[(size_t)n * 128 + tx * 4]      = make_float4(o[0], o[1], o[2], o[3]);
            *(float4*)&out[(size_t)n * 128 + 64 + tx * 4] = make_float4(o[4], o[5], o[6], o[7]);
        }
    }
}

// ---------------- decode ----------------
// 4 label-edges per wave; 16 lanes x float4 per endpoint row.

__global__ void k_decode(const int* __restrict__ eli, const float* __restrict__ z,
                         float* __restrict__ out) {
    int w = blockIdx.x * 4 + (threadIdx.x >> 6);
    int lane = threadIdx.x & 63;
    int sub = lane >> 4, li = lane & 15;
    int e = w * 4 + sub;
    if (e >= NL) return;
    int a = eli[e], b = eli[NL + e];
    float4 va = *(const float4*)&z[(size_t)a * 64 + li * 4];
    float4 vb = *(const float4*)&z[(size_t)b * 64 + li * 4];
    float s = va.x * vb.x + va.y * vb.y + va.z * vb.z + va.w * vb.w;
    s += __shfl_xor(s, 1, 64);
    s += __shfl_xor(s, 2, 64);
    s += __shfl_xor(s, 4, 64);
    s += __shfl_xor(s, 8, 64);
    if (li == 0) out[e] = s;
}

// ---------------- launch ----------------

extern "C" void kernel_launch(void* const* d_in, const int* in_sizes, int n_in,
                              void* d_out, int out_size, void* d_ws, size_t ws_size,
                              hipStream_t stream) {
    const float* x   = (const float*)d_in[0];
    const int*   edge = (const int*)d_in[1];   // [2, NE]
    const int*   eli  = (const int*)d_in[2];   // [2, NL]
    const float* Wl1 = (const float*)d_in[3];
    const float* Wr1 = (const float*)d_in[4];
    const float* b1  = (const float*)d_in[5];
    const float* Wl2 = (const float*)d_in[6];
    const float* Wr2 = (const float*)d_in[7];
    const float* b2  = (const float*)d_in[8];
    const float* Wl3 = (const float*)d_in[9];
    const float* Wr3 = (const float*)d_in[10];
    const float* b3  = (const float*)d_in[11];
    float* out = (float*)d_out;

    char* w = (char*)d_ws;
    auto carve = [&](size_t bytes) {
        char* p = w;
        w += (bytes + 255) & ~(size_t)255;
        return p;
    };
    int*   rowptr = (int*)carve((NN + 1) * sizeof(int));
    int*   cursor = (int*)carve(NN * sizeof(int));        // doubles as counts
    int*   csr    = (int*)carve(NE * sizeof(int));
    int*   bsum   = (int*)carve(256 * sizeof(int));
    float* M      = (float*)carve((size_t)NN * 64 * sizeof(float));   // mean1, later z
    float* A      = (float*)carve((size_t)NN * 128 * sizeof(float));  // h1
    float* B      = (float*)carve((size_t)NN * 128 * sizeof(float));  // mean2, later pq
    float* C      = (float*)carve((size_t)NN * 128 * sizeof(float));  // h2

    const int* src = edge;
    const int* tgt = edge + NE;

    hipMemsetAsync(cursor, 0, NN * sizeof(int), stream);
    k_count<<<(NE + 255) / 256, 256, 0, stream>>>(tgt, cursor);
    k_scan1<<<NB_SCAN, 256, 0, stream>>>(cursor, bsum);
    k_scan2<<<1, 256, 0, stream>>>(bsum, NB_SCAN);
    k_scan3<<<NB_SCAN, 256, 0, stream>>>(cursor, bsum, rowptr, cursor);
    k_fill<<<(NE + 255) / 256, 256, 0, stream>>>(src, tgt, cursor, csr);

    // layer 1: mean1 = mean(x); h1 = relu([mean1|x] @ [Wl1;Wr1] + b1)
    k_agg<64><<<(NN + 3) / 4, 256, 0, stream>>>(x, 64, nullptr, 0, M, 64, rowptr, csr);
    k_gemm<128, 64, 0, 1><<<(NN + 63) / 64, 256, 0, stream>>>(M, x, Wl1, Wr1, b1, A);

    // layer 2: mean2 = mean(h1); h2 = relu([mean2|h1] @ [Wl2;Wr2] + b2)
    k_agg<128><<<(NN + 3) / 4, 256, 0, stream>>>(A, 128, nullptr, 0, B, 128, rowptr, csr);
    k_gemm<256, 128, 0, 1><<<(NN + 63) / 64, 256, 0, stream>>>(B, A, Wl2, Wr2, b2, C);

    // layer 3 (GEMM first, then scatter 64-wide): pq = h2 @ [Wl3 | Wr3]; q gets b3
    k_gemm<128, 128, 1, 0><<<(NN + 63) / 64, 256, 0, stream>>>(C, nullptr, Wl3, Wr3, b3, B);
    // z = scatter_mean(p) + q
    k_agg<64><<<(NN + 3) / 4, 256, 0, stream>>>(B, 128, B + 64, 128, M, 64, rowptr, csr);

    // decode: out[l] = dot(z[a], z[b])
    k_decode<<<(NL + 15) / 16, 256, 0, stream>>>(eli, M, out);
}

// Round 8
// 356.357 us; speedup vs baseline: 1.6014x; 1.0175x over previous
//
#include <hip/hip_runtime.h>

#define NN 50000
#define NE 800000
#define NL 200000
#define NB_SCAN 196  // ceil(50000/256)

// ---------------- CSR build ----------------

__global__ void k_count(const int* __restrict__ tgt, int* __restrict__ counts) {
    int e = blockIdx.x * blockDim.x + threadIdx.x;
    if (e < NE) atomicAdd(&counts[tgt[e]], 1);
}

__global__ void k_scan1(const int* __restrict__ counts, int* __restrict__ bsum) {
    int i = blockIdx.x * 256 + threadIdx.x;
    int v = (i < NN) ? counts[i] : 0;
    #pragma unroll
    for (int off = 32; off; off >>= 1) v += __shfl_down(v, off, 64);
    __shared__ int ws4[4];
    int wave = threadIdx.x >> 6, lane = threadIdx.x & 63;
    if (lane == 0) ws4[wave] = v;
    __syncthreads();
    if (threadIdx.x == 0) bsum[blockIdx.x] = ws4[0] + ws4[1] + ws4[2] + ws4[3];
}

__global__ void k_scan2(int* __restrict__ bsum, int nb) {
    __shared__ int s[256];
    int t = threadIdx.x;
    int v = (t < nb) ? bsum[t] : 0;
    s[t] = v;
    __syncthreads();
    for (int off = 1; off < 256; off <<= 1) {
        int a = (t >= off) ? s[t - off] : 0;
        __syncthreads();
        s[t] += a;
        __syncthreads();
    }
    if (t < nb) bsum[t] = s[t] - v;  // exclusive
}

__global__ void k_scan3(const int* __restrict__ counts, const int* __restrict__ boff,
                        int* __restrict__ rowptr, int* __restrict__ cursor) {
    __shared__ int s[256];
    int t = threadIdx.x;
    int i = blockIdx.x * 256 + t;
    int v = (i < NN) ? counts[i] : 0;
    s[t] = v;
    __syncthreads();
    for (int off = 1; off < 256; off <<= 1) {
        int a = (t >= off) ? s[t - off] : 0;
        __syncthreads();
        s[t] += a;
        __syncthreads();
    }
    int excl = s[t] - v + boff[blockIdx.x];
    if (i < NN) { rowptr[i] = excl; cursor[i] = excl; }
    if (i == NN - 1) rowptr[NN] = excl + v;  // == NE
}

__global__ void k_fill(const int* __restrict__ src, const int* __restrict__ tgt,
                       int* __restrict__ cursor, int* __restrict__ csr) {
    int e = blockIdx.x * blockDim.x + threadIdx.x;
    if (e < NE) {
        int p = atomicAdd(&cursor[tgt[e]], 1);
        csr[p] = src[e];
    }
}

// ---------------- CSR gather-mean aggregation ----------------
// One wave per node; EPW edge-slots of LPR lanes each, float4 per lane.
// TWO interleaved edge streams per slot (2x outstanding gathers) with
// prefetched csr indices to break the index->gather dependency chain.

template <int D>
__global__ void k_agg(const float* __restrict__ in, int inStride,
                      const float* __restrict__ addp, int addStride,
                      float* __restrict__ out, int outStride,
                      const int* __restrict__ rowptr, const int* __restrict__ csr) {
    constexpr int LPR = D / 4;      // lanes per row: 16 (D=64) or 32 (D=128)
    constexpr int EPW = 64 / LPR;   // edge slots per wave: 4 or 2
    int node = blockIdx.x * 4 + (threadIdx.x >> 6);
    int lane = threadIdx.x & 63;
    if (node >= NN) return;
    int sub = lane / LPR;           // edge slot
    int li  = lane % LPR;           // float4 index within row
    int r0 = rowptr[node], r1 = rowptr[node + 1];

    float4 a0 = make_float4(0.f, 0.f, 0.f, 0.f);
    float4 a1 = make_float4(0.f, 0.f, 0.f, 0.f);
    int e0 = r0 + sub;              // stream 0: e0, e0+2*EPW, ...
    int e1 = e0 + EPW;              // stream 1: e1, e1+2*EPW, ...
    int i0 = (e0 < r1) ? csr[e0] : 0;
    int i1 = (e1 < r1) ? csr[e1] : 0;
    while (e1 < r1) {
        int e0n = e0 + 2 * EPW, e1n = e1 + 2 * EPW;
        int i0n = (e0n < r1) ? csr[e0n] : 0;
        int i1n = (e1n < r1) ? csr[e1n] : 0;
        float4 v0 = ((const float4*)(in + (size_t)i0 * inStride))[li];
        float4 v1 = ((const float4*)(in + (size_t)i1 * inStride))[li];
        a0.x += v0.x; a0.y += v0.y; a0.z += v0.z; a0.w += v0.w;
        a1.x += v1.x; a1.y += v1.y; a1.z += v1.z; a1.w += v1.w;
        e0 = e0n; e1 = e1n; i0 = i0n; i1 = i1n;
    }
    if (e0 < r1) {  // at most one leftover in stream 0
        float4 v0 = ((const float4*)(in + (size_t)i0 * inStride))[li];
        a0.x += v0.x; a0.y += v0.y; a0.z += v0.z; a0.w += v0.w;
    }
    a0.x += a1.x; a0.y += a1.y; a0.z += a1.z; a0.w += a1.w;
    // reduce across edge slots (lanes sharing li)
    #pragma unroll
    for (int off = LPR; off < 64; off <<= 1) {
        a0.x += __shfl_xor(a0.x, off, 64);
        a0.y += __shfl_xor(a0.y, off, 64);
        a0.z += __shfl_xor(a0.z, off, 64);
        a0.w += __shfl_xor(a0.w, off, 64);
    }
    if (sub == 0) {
        float inv = 1.0f / fmaxf((float)(r1 - r0), 1.0f);
        a0.x *= inv; a0.y *= inv; a0.z *= inv; a0.w *= inv;
        if (addp) {
            float4 a = *(const float4*)&addp[(size_t)node * addStride + li * 4];
            a0.x += a.x; a0.y += a.y; a0.z += a.z; a0.w += a.w;
        }
        *(float4*)&out[(size_t)node * outStride + li * 4] = a0;
    }
}

// ---------------- fused GEMM ----------------
// Tile: 32 nodes x 128 cols per 256-thread block (1563 blocks -> ~6/CU).
// Micro-tile 2 rows x 8 cols; cols split {tx*4, 64+tx*4} (2-way bank alias =
// free). LDS 21.2 KB/block.
// KCAT (NCAT=0): out = [inA | inB] @ [W1 ; W2] + bias, optional ReLU.
// NCAT=1: out cols 0..63 = inA @ W1 (no bias), cols 64..127 = inA @ W2 + bias.

template <int K, int KA, int NCAT, int RELU>
__global__ void k_gemm(const float* __restrict__ inA, const float* __restrict__ inB,
                       const float* __restrict__ W1, const float* __restrict__ W2,
                       const float* __restrict__ bias, float* __restrict__ out) {
    constexpr int KB = K - KA;
    constexpr int KC = 32;
    __shared__ float sIn[KC][34];    // transposed input tile [k][node], padded
    __shared__ float sW[KC][132];    // weight tile [k][col], padded

    int tid = threadIdx.x;
    int tx = tid & 15;               // col group: {tx*4..+3} and {64+tx*4..+3}
    int ty = tid >> 4;               // row group: rows ty*2..ty*2+1
    int bn = blockIdx.x * 32;

    float acc[2][8];
    #pragma unroll
    for (int i = 0; i < 2; i++)
        #pragma unroll
        for (int j = 0; j < 8; j++) acc[i][j] = 0.f;

    int ln = tid >> 3;               // node 0..31 within tile
    int lk = (tid & 7) * 4;          // k offset 0,4,...,28
    int gn = min(bn + ln, NN - 1);
    int wk = tid >> 3;               // 0..31
    int wc = (tid & 7) * 16;         // 0..112

    for (int k0 = 0; k0 < K; k0 += KC) {
        // stage input (transposed): 1 float4 per thread
        {
            int kg = k0 + lk;
            float4 v;
            if constexpr (NCAT) {
                v = *(const float4*)&inA[(size_t)gn * K + kg];
            } else {
                if (kg < KA) v = *(const float4*)&inA[(size_t)gn * KA + kg];
                else         v = *(const float4*)&inB[(size_t)gn * KB + (kg - KA)];
            }
            sIn[lk + 0][ln] = v.x; sIn[lk + 1][ln] = v.y;
            sIn[lk + 2][ln] = v.z; sIn[lk + 3][ln] = v.w;
        }
        // stage weights: 4 float4 per thread
        #pragma unroll
        for (int i = 0; i < 4; i++) {
            int c = wc + i * 4;
            int kg = k0 + wk;
            float4 w;
            if constexpr (NCAT) {
                if (c < 64) w = *(const float4*)&W1[(size_t)kg * 64 + c];
                else        w = *(const float4*)&W2[(size_t)kg * 64 + (c - 64)];
            } else {
                if (kg < KA) w = *(const float4*)&W1[(size_t)kg * 128 + c];
                else         w = *(const float4*)&W2[(size_t)(kg - KA) * 128 + c];
            }
            *(float4*)&sW[wk][c] = w;
        }
        __syncthreads();

        #pragma unroll
        for (int kk = 0; kk < KC; kk++) {
            float2 av = *(float2*)&sIn[kk][ty * 2];
            float4 w0 = *(float4*)&sW[kk][tx * 4];
            float4 w1 = *(float4*)&sW[kk][64 + tx * 4];
            float a[2] = {av.x, av.y};
            float w[8] = {w0.x, w0.y, w0.z, w0.w, w1.x, w1.y, w1.z, w1.w};
            #pragma unroll
            for (int i = 0; i < 2; i++)
                #pragma unroll
                for (int j = 0; j < 8; j++) acc[i][j] += a[i] * w[j];
        }
        __syncthreads();
    }

    // epilogue: bias (+ReLU) and store
    float bc[8];
    #pragma unroll
    for (int j = 0; j < 8; j++) {
        int c = (j < 4) ? (tx * 4 + j) : (64 + tx * 4 + (j - 4));
        if constexpr (NCAT) bc[j] = (c < 64) ? 0.f : bias[c - 64];
        else bc[j] = bias[c];
    }
    #pragma unroll
    for (int i = 0; i < 2; i++) {
        int n = bn + ty * 2 + i;
        if (n < NN) {
            float o[8];
            #pragma unroll
            for (int j = 0; j < 8; j++) {
                float v = acc[i][j] + bc[j];
                o[j] = RELU ? fmaxf(v, 0.f) : v;
            }
            *(float4*)&out[(size_t)n * 128 + tx * 4]      = make_float4(o[0], o[1], o[2], o[3]);
            *(float4*)&out[(size_t)n * 128 + 64 + tx * 4] = make_float4(o[4], o[5], o[6], o[7]);
        }
    }
}

// ---------------- decode ----------------
// 8 label-edges per wave: 4 slots x 16 lanes x float4, 2 edges per slot.

__global__ void k_decode(const int* __restrict__ eli, const float* __restrict__ z,
                         float* __restrict__ out) {
    int w = blockIdx.x * 4 + (threadIdx.x >> 6);
    int lane = threadIdx.x & 63;
    int sub = lane >> 4, li = lane & 15;
    int e0 = w * 8 + sub;
    int e1 = e0 + 4;
    float s0 = 0.f, s1 = 0.f;
    if (e0 < NL) {
        int a = eli[e0], b = eli[NL + e0];
        float4 va = *(const float4*)&z[(size_t)a * 64 + li * 4];
        float4 vb = *(const float4*)&z[(size_t)b * 64 + li * 4];
        s0 = va.x * vb.x + va.y * vb.y + va.z * vb.z + va.w * vb.w;
    }
    if (e1 < NL) {
        int a = eli[e1], b = eli[NL + e1];
        float4 va = *(const float4*)&z[(size_t)a * 64 + li * 4];
        float4 vb = *(const float4*)&z[(size_t)b * 64 + li * 4];
        s1 = va.x * vb.x + va.y * vb.y + va.z * vb.z + va.w * vb.w;
    }
    #pragma unroll
    for (int off = 1; off < 16; off <<= 1) {
        s0 += __shfl_xor(s0, off, 64);
        s1 += __shfl_xor(s1, off, 64);
    }
    if (li == 0) {
        if (e0 < NL) out[e0] = s0;
        if (e1 < NL) out[e1] = s1;
    }
}

// ---------------- launch ----------------

extern "C" void kernel_launch(void* const* d_in, const int* in_sizes, int n_in,
                              void* d_out, int out_size, void* d_ws, size_t ws_size,
                              hipStream_t stream) {
    const float* x   = (const float*)d_in[0];
    const int*   edge = (const int*)d_in[1];   // [2, NE]
    const int*   eli  = (const int*)d_in[2];   // [2, NL]
    const float* Wl1 = (const float*)d_in[3];
    const float* Wr1 = (const float*)d_in[4];
    const float* b1  = (const float*)d_in[5];
    const float* Wl2 = (const float*)d_in[6];
    const float* Wr2 = (const float*)d_in[7];
    const float* b2  = (const float*)d_in[8];
    const float* Wl3 = (const float*)d_in[9];
    const float* Wr3 = (const float*)d_in[10];
    const float* b3  = (const float*)d_in[11];
    float* out = (float*)d_out;

    char* w = (char*)d_ws;
    auto carve = [&](size_t bytes) {
        char* p = w;
        w += (bytes + 255) & ~(size_t)255;
        return p;
    };
    int*   rowptr = (int*)carve((NN + 1) * sizeof(int));
    int*   cursor = (int*)carve(NN * sizeof(int));        // doubles as counts
    int*   csr    = (int*)carve(NE * sizeof(int));
    int*   bsum   = (int*)carve(256 * sizeof(int));
    float* M      = (float*)carve((size_t)NN * 64 * sizeof(float));   // mean1, later z
    float* A      = (float*)carve((size_t)NN * 128 * sizeof(float));  // h1
    float* B      = (float*)carve((size_t)NN * 128 * sizeof(float));  // mean2, later pq
    float* C      = (float*)carve((size_t)NN * 128 * sizeof(float));  // h2

    const int* src = edge;
    const int* tgt = edge + NE;

    hipMemsetAsync(cursor, 0, NN * sizeof(int), stream);
    k_count<<<(NE + 255) / 256, 256, 0, stream>>>(tgt, cursor);
    k_scan1<<<NB_SCAN, 256, 0, stream>>>(cursor, bsum);
    k_scan2<<<1, 256, 0, stream>>>(bsum, NB_SCAN);
    k_scan3<<<NB_SCAN, 256, 0, stream>>>(cursor, bsum, rowptr, cursor);
    k_fill<<<(NE + 255) / 256, 256, 0, stream>>>(src, tgt, cursor, csr);

    // layer 1: mean1 = mean(x); h1 = relu([mean1|x] @ [Wl1;Wr1] + b1)
    k_agg<64><<<(NN + 3) / 4, 256, 0, stream>>>(x, 64, nullptr, 0, M, 64, rowptr, csr);
    k_gemm<128, 64, 0, 1><<<(NN + 31) / 32, 256, 0, stream>>>(M, x, Wl1, Wr1, b1, A);

    // layer 2: mean2 = mean(h1); h2 = relu([mean2|h1] @ [Wl2;Wr2] + b2)
    k_agg<128><<<(NN + 3) / 4, 256, 0, stream>>>(A, 128, nullptr, 0, B, 128, rowptr, csr);
    k_gemm<256, 128, 0, 1><<<(NN + 31) / 32, 256, 0, stream>>>(B, A, Wl2, Wr2, b2, C);

    // layer 3 (GEMM first, then scatter 64-wide): pq = h2 @ [Wl3 | Wr3]; q gets b3
    k_gemm<128, 128, 1, 0><<<(NN + 31) / 32, 256, 0, stream>>>(C, nullptr, Wl3, Wr3, b3, B);
    // z = scatter_mean(p) + q
    k_agg<64><<<(NN + 3) / 4, 256, 0, stream>>>(B, 128, B + 64, 128, M, 64, rowptr, csr);

    // decode: out[l] = dot(z[a], z[b])
    k_decode<<<(NL + 31) / 32, 256, 0, stream>>>(eli, M, out);
}

// Round 9
// 334.099 us; speedup vs baseline: 1.7081x; 1.0666x over previous
//
#include <hip/hip_runtime.h>

#define NN 50000
#define NE 800000
#define NL 200000
#define NB_SCAN 196  // ceil(50000/256)

typedef __attribute__((ext_vector_type(8))) short bf16x8;
typedef __attribute__((ext_vector_type(4))) float f32x4;

__device__ __forceinline__ ushort bf16_rne(float f) {
    union { float f; unsigned u; } v; v.f = f;
    unsigned r = v.u + 0x7FFF + ((v.u >> 16) & 1);
    return (ushort)(r >> 16);
}
__device__ __forceinline__ float bf16_to_f(ushort h) {
    union { unsigned u; float f; } v; v.u = ((unsigned)h) << 16;
    return v.f;
}

// ---------------- CSR build ----------------

__global__ void k_count(const int* __restrict__ tgt, int* __restrict__ counts) {
    int e = blockIdx.x * blockDim.x + threadIdx.x;
    if (e < NE) atomicAdd(&counts[tgt[e]], 1);
}

__global__ void k_scan1(const int* __restrict__ counts, int* __restrict__ bsum) {
    int i = blockIdx.x * 256 + threadIdx.x;
    int v = (i < NN) ? counts[i] : 0;
    #pragma unroll
    for (int off = 32; off; off >>= 1) v += __shfl_down(v, off, 64);
    __shared__ int ws4[4];
    int wave = threadIdx.x >> 6, lane = threadIdx.x & 63;
    if (lane == 0) ws4[wave] = v;
    __syncthreads();
    if (threadIdx.x == 0) bsum[blockIdx.x] = ws4[0] + ws4[1] + ws4[2] + ws4[3];
}

__global__ void k_scan2(int* __restrict__ bsum, int nb) {
    __shared__ int s[256];
    int t = threadIdx.x;
    int v = (t < nb) ? bsum[t] : 0;
    s[t] = v;
    __syncthreads();
    for (int off = 1; off < 256; off <<= 1) {
        int a = (t >= off) ? s[t - off] : 0;
        __syncthreads();
        s[t] += a;
        __syncthreads();
    }
    if (t < nb) bsum[t] = s[t] - v;  // exclusive
}

__global__ void k_scan3(const int* __restrict__ counts, const int* __restrict__ boff,
                        int* __restrict__ rowptr, int* __restrict__ cursor) {
    __shared__ int s[256];
    int t = threadIdx.x;
    int i = blockIdx.x * 256 + t;
    int v = (i < NN) ? counts[i] : 0;
    s[t] = v;
    __syncthreads();
    for (int off = 1; off < 256; off <<= 1) {
        int a = (t >= off) ? s[t - off] : 0;
        __syncthreads();
        s[t] += a;
        __syncthreads();
    }
    int excl = s[t] - v + boff[blockIdx.x];
    if (i < NN) { rowptr[i] = excl; cursor[i] = excl; }
    if (i == NN - 1) rowptr[NN] = excl + v;  // == NE
}

__global__ void k_fill(const int* __restrict__ src, const int* __restrict__ tgt,
                       int* __restrict__ cursor, int* __restrict__ csr) {
    int e = blockIdx.x * blockDim.x + threadIdx.x;
    if (e < NE) {
        int p = atomicAdd(&cursor[tgt[e]], 1);
        csr[p] = src[e];
    }
}

// ---------------- CSR gather-mean aggregation ----------------
// One wave per node; EPW edge-slots of LPR lanes each, float4 per lane.
// TWO interleaved edge streams per slot with prefetched csr indices.

template <int D>
__global__ void k_agg(const float* __restrict__ in, int inStride,
                      const float* __restrict__ addp, int addStride,
                      float* __restrict__ out, int outStride,
                      const int* __restrict__ rowptr, const int* __restrict__ csr) {
    constexpr int LPR = D / 4;      // lanes per row: 16 (D=64) or 32 (D=128)
    constexpr int EPW = 64 / LPR;   // edge slots per wave: 4 or 2
    int node = blockIdx.x * 4 + (threadIdx.x >> 6);
    int lane = threadIdx.x & 63;
    if (node >= NN) return;
    int sub = lane / LPR;           // edge slot
    int li  = lane % LPR;           // float4 index within row
    int r0 = rowptr[node], r1 = rowptr[node + 1];

    float4 a0 = make_float4(0.f, 0.f, 0.f, 0.f);
    float4 a1 = make_float4(0.f, 0.f, 0.f, 0.f);
    int e0 = r0 + sub;
    int e1 = e0 + EPW;
    int i0 = (e0 < r1) ? csr[e0] : 0;
    int i1 = (e1 < r1) ? csr[e1] : 0;
    while (e1 < r1) {
        int e0n = e0 + 2 * EPW, e1n = e1 + 2 * EPW;
        int i0n = (e0n < r1) ? csr[e0n] : 0;
        int i1n = (e1n < r1) ? csr[e1n] : 0;
        float4 v0 = ((const float4*)(in + (size_t)i0 * inStride))[li];
        float4 v1 = ((const float4*)(in + (size_t)i1 * inStride))[li];
        a0.x += v0.x; a0.y += v0.y; a0.z += v0.z; a0.w += v0.w;
        a1.x += v1.x; a1.y += v1.y; a1.z += v1.z; a1.w += v1.w;
        e0 = e0n; e1 = e1n; i0 = i0n; i1 = i1n;
    }
    if (e0 < r1) {
        float4 v0 = ((const float4*)(in + (size_t)i0 * inStride))[li];
        a0.x += v0.x; a0.y += v0.y; a0.z += v0.z; a0.w += v0.w;
    }
    a0.x += a1.x; a0.y += a1.y; a0.z += a1.z; a0.w += a1.w;
    #pragma unroll
    for (int off = LPR; off < 64; off <<= 1) {
        a0.x += __shfl_xor(a0.x, off, 64);
        a0.y += __shfl_xor(a0.y, off, 64);
        a0.z += __shfl_xor(a0.z, off, 64);
        a0.w += __shfl_xor(a0.w, off, 64);
    }
    if (sub == 0) {
        float inv = 1.0f / fmaxf((float)(r1 - r0), 1.0f);
        a0.x *= inv; a0.y *= inv; a0.z *= inv; a0.w *= inv;
        if (addp) {
            float4 a = *(const float4*)&addp[(size_t)node * addStride + li * 4];
            a0.x += a.x; a0.y += a.y; a0.z += a.z; a0.w += a.w;
        }
        *(float4*)&out[(size_t)node * outStride + li * 4] = a0;
    }
}

// ---------------- MFMA GEMM (bf16x3 split = fp32 accuracy) ----------------
// out[M x 128] = In[M x K] @ W[K x 128] (+bias, relu).
// C = Ah@Wh + Ah@Wl + Al@Wh  (Xh = bf16(X), Xl = bf16(X - Xh); AlWl ~2^-18, dropped)
// Block: 256 thr = 4 waves, 128 rows. Wave: 2 row-tiles(16) x 8 col-tiles(16).
// Per 32-k chunk: stage W-chunk hi/lo bf16 TRANSPOSED in LDS [128 cols][40 pad]
// (40 ushorts = 80B row: 16B-aligned b128 reads, <=2-way banks). A-frags read
// direct from global (each element once), converted hi/lo in-reg.
// MFMA layouts (m89-verified C/D; standard A/B): A[j]=A[l&15][(l>>4)*8+j],
// B[j]=B[(l>>4)*8+j][l&15], D[j]=C[(l>>4)*4+j][l&15].

template <int K, int KA, int NCAT, int RELU>
__global__ void k_mgemm(const float* __restrict__ inA, const float* __restrict__ inB,
                        const float* __restrict__ W1, const float* __restrict__ W2,
                        const float* __restrict__ bias, float* __restrict__ out) {
    constexpr int KB = K - KA;
    __shared__ ushort sWh[128][40];
    __shared__ ushort sWl[128][40];

    int tid = threadIdx.x;
    int wave = tid >> 6, lane = tid & 63;
    int lr  = lane & 15;          // row (A) / col (B,D) within tile
    int kg4 = lane >> 4;          // k-group 0..3
    int rbase = blockIdx.x * 128 + wave * 32;
    int r0 = min(rbase + lr, NN - 1);
    int r1 = min(rbase + 16 + lr, NN - 1);

    // staging mapping: r = k-row within chunk, cg*16.. = col window
    int sr = tid & 31, cg = tid >> 5;

    f32x4 acc[2][8];
    #pragma unroll
    for (int rt = 0; rt < 2; rt++)
        #pragma unroll
        for (int ct = 0; ct < 8; ct++) acc[rt][ct] = (f32x4){0.f, 0.f, 0.f, 0.f};

    for (int k0 = 0; k0 < K; k0 += 32) {
        // ---- stage W chunk (hi/lo, transposed) ----
        {
            int kg = k0 + sr;
            #pragma unroll
            for (int i = 0; i < 4; i++) {
                int c = cg * 16 + i * 4;
                float4 w;
                if constexpr (NCAT) {
                    if (c < 64) w = *(const float4*)&W1[(size_t)kg * 64 + c];
                    else        w = *(const float4*)&W2[(size_t)kg * 64 + (c - 64)];
                } else {
                    if (kg < KA) w = *(const float4*)&W1[(size_t)kg * 128 + c];
                    else         w = *(const float4*)&W2[(size_t)(kg - KA) * 128 + c];
                }
                float wf[4] = {w.x, w.y, w.z, w.w};
                #pragma unroll
                for (int q = 0; q < 4; q++) {
                    ushort h = bf16_rne(wf[q]);
                    ushort l = bf16_rne(wf[q] - bf16_to_f(h));
                    sWh[c + q][sr] = h;
                    sWl[c + q][sr] = l;
                }
            }
        }
        __syncthreads();

        // ---- A-frags for 2 row-tiles (hi/lo) ----
        bf16x8 ah[2], al[2];
        #pragma unroll
        for (int rt = 0; rt < 2; rt++) {
            int row = (rt == 0) ? r0 : r1;
            int kg2 = k0 + kg4 * 8;
            float4 v0, v1;
            if constexpr (NCAT) {
                v0 = *(const float4*)&inA[(size_t)row * K + kg2];
                v1 = *(const float4*)&inA[(size_t)row * K + kg2 + 4];
            } else {
                if (kg2 < KA) v0 = *(const float4*)&inA[(size_t)row * KA + kg2];
                else          v0 = *(const float4*)&inB[(size_t)row * KB + (kg2 - KA)];
                if (kg2 + 4 < KA) v1 = *(const float4*)&inA[(size_t)row * KA + kg2 + 4];
                else              v1 = *(const float4*)&inB[(size_t)row * KB + (kg2 + 4 - KA)];
            }
            float av[8] = {v0.x, v0.y, v0.z, v0.w, v1.x, v1.y, v1.z, v1.w};
            #pragma unroll
            for (int j = 0; j < 8; j++) {
                ushort h = bf16_rne(av[j]);
                ushort l = bf16_rne(av[j] - bf16_to_f(h));
                ah[rt][j] = (short)h;
                al[rt][j] = (short)l;
            }
        }

        // ---- MFMA over 8 col-tiles ----
        #pragma unroll
        for (int ct = 0; ct < 8; ct++) {
            bf16x8 bh = *(const bf16x8*)&sWh[ct * 16 + lr][kg4 * 8];
            bf16x8 bl = *(const bf16x8*)&sWl[ct * 16 + lr][kg4 * 8];
            #pragma unroll
            for (int rt = 0; rt < 2; rt++) {
                acc[rt][ct] = __builtin_amdgcn_mfma_f32_16x16x32_bf16(ah[rt], bh, acc[rt][ct], 0, 0, 0);
                acc[rt][ct] = __builtin_amdgcn_mfma_f32_16x16x32_bf16(ah[rt], bl, acc[rt][ct], 0, 0, 0);
                acc[rt][ct] = __builtin_amdgcn_mfma_f32_16x16x32_bf16(al[rt], bh, acc[rt][ct], 0, 0, 0);
            }
        }
        __syncthreads();
    }

    // ---- epilogue: bias (+ReLU), store ----
    float bc[8];
    #pragma unroll
    for (int ct = 0; ct < 8; ct++) {
        int c = ct * 16 + lr;
        if constexpr (NCAT) bc[ct] = (c < 64) ? 0.f : bias[c - 64];
        else bc[ct] = bias[c];
    }
    #pragma unroll
    for (int rt = 0; rt < 2; rt++) {
        #pragma unroll
        for (int j = 0; j < 4; j++) {
            int n = rbase + rt * 16 + kg4 * 4 + j;
            if (n < NN) {
                float* orow = &out[(size_t)n * 128 + lr];
                #pragma unroll
                for (int ct = 0; ct < 8; ct++) {
                    float v = acc[rt][ct][j] + bc[ct];
                    if (RELU) v = fmaxf(v, 0.f);
                    orow[ct * 16] = v;
                }
            }
        }
    }
}

// ---------------- decode ----------------
// 8 label-edges per wave: 4 slots x 16 lanes x float4, 2 edges per slot.

__global__ void k_decode(const int* __restrict__ eli, const float* __restrict__ z,
                         float* __restrict__ out) {
    int w = blockIdx.x * 4 + (threadIdx.x >> 6);
    int lane = threadIdx.x & 63;
    int sub = lane >> 4, li = lane & 15;
    int e0 = w * 8 + sub;
    int e1 = e0 + 4;
    float s0 = 0.f, s1 = 0.f;
    if (e0 < NL) {
        int a = eli[e0], b = eli[NL + e0];
        float4 va = *(const float4*)&z[(size_t)a * 64 + li * 4];
        float4 vb = *(const float4*)&z[(size_t)b * 64 + li * 4];
        s0 = va.x * vb.x + va.y * vb.y + va.z * vb.z + va.w * vb.w;
    }
    if (e1 < NL) {
        int a = eli[e1], b = eli[NL + e1];
        float4 va = *(const float4*)&z[(size_t)a * 64 + li * 4];
        float4 vb = *(const float4*)&z[(size_t)b * 64 + li * 4];
        s1 = va.x * vb.x + va.y * vb.y + va.z * vb.z + va.w * vb.w;
    }
    #pragma unroll
    for (int off = 1; off < 16; off <<= 1) {
        s0 += __shfl_xor(s0, off, 64);
        s1 += __shfl_xor(s1, off, 64);
    }
    if (li == 0) {
        if (e0 < NL) out[e0] = s0;
        if (e1 < NL) out[e1] = s1;
    }
}

// ---------------- launch ----------------

extern "C" void kernel_launch(void* const* d_in, const int* in_sizes, int n_in,
                              void* d_out, int out_size, void* d_ws, size_t ws_size,
                              hipStream_t stream) {
    const float* x   = (const float*)d_in[0];
    const int*   edge = (const int*)d_in[1];   // [2, NE]
    const int*   eli  = (const int*)d_in[2];   // [2, NL]
    const float* Wl1 = (const float*)d_in[3];
    const float* Wr1 = (const float*)d_in[4];
    const float* b1  = (const float*)d_in[5];
    const float* Wl2 = (const float*)d_in[6];
    const float* Wr2 = (const float*)d_in[7];
    const float* b2  = (const float*)d_in[8];
    const float* Wl3 = (const float*)d_in[9];
    const float* Wr3 = (const float*)d_in[10];
    const float* b3  = (const float*)d_in[11];
    float* out = (float*)d_out;

    char* w = (char*)d_ws;
    auto carve = [&](size_t bytes) {
        char* p = w;
        w += (bytes + 255) & ~(size_t)255;
        return p;
    };
    int*   rowptr = (int*)carve((NN + 1) * sizeof(int));
    int*   cursor = (int*)carve(NN * sizeof(int));        // doubles as counts
    int*   csr    = (int*)carve(NE * sizeof(int));
    int*   bsum   = (int*)carve(256 * sizeof(int));
    float* M      = (float*)carve((size_t)NN * 64 * sizeof(float));   // mean1, later z
    float* A      = (float*)carve((size_t)NN * 128 * sizeof(float));  // h1
    float* B      = (float*)carve((size_t)NN * 128 * sizeof(float));  // mean2, later pq
    float* C      = (float*)carve((size_t)NN * 128 * sizeof(float));  // h2

    const int* src = edge;
    const int* tgt = edge + NE;

    hipMemsetAsync(cursor, 0, NN * sizeof(int), stream);
    k_count<<<(NE + 255) / 256, 256, 0, stream>>>(tgt, cursor);
    k_scan1<<<NB_SCAN, 256, 0, stream>>>(cursor, bsum);
    k_scan2<<<1, 256, 0, stream>>>(bsum, NB_SCAN);
    k_scan3<<<NB_SCAN, 256, 0, stream>>>(cursor, bsum, rowptr, cursor);
    k_fill<<<(NE + 255) / 256, 256, 0, stream>>>(src, tgt, cursor, csr);

    // layer 1: mean1 = mean(x); h1 = relu([mean1|x] @ [Wl1;Wr1] + b1)
    k_agg<64><<<(NN + 3) / 4, 256, 0, stream>>>(x, 64, nullptr, 0, M, 64, rowptr, csr);
    k_mgemm<128, 64, 0, 1><<<(NN + 127) / 128, 256, 0, stream>>>(M, x, Wl1, Wr1, b1, A);

    // layer 2: mean2 = mean(h1); h2 = relu([mean2|h1] @ [Wl2;Wr2] + b2)
    k_agg<128><<<(NN + 3) / 4, 256, 0, stream>>>(A, 128, nullptr, 0, B, 128, rowptr, csr);
    k_mgemm<256, 128, 0, 1><<<(NN + 127) / 128, 256, 0, stream>>>(B, A, Wl2, Wr2, b2, C);

    // layer 3 (GEMM first, then scatter 64-wide): pq = h2 @ [Wl3 | Wr3]; q gets b3
    k_mgemm<128, 128, 1, 0><<<(NN + 127) / 128, 256, 0, stream>>>(C, nullptr, Wl3, Wr3, b3, B);
    // z = scatter_mean(p) + q
    k_agg<64><<<(NN + 3) / 4, 256, 0, stream>>>(B, 128, B + 64, 128, M, 64, rowptr, csr);

    // decode: out[l] = dot(z[a], z[b])
    k_decode<<<(NL + 31) / 32, 256, 0, stream>>>(eli, M, out);
}

// Round 10
// 295.838 us; speedup vs baseline: 1.9290x; 1.1293x over previous
//
#include <hip/hip_runtime.h>

#define NN 50000
#define NE 800000
#define NL 200000
#define NB_SCAN 196  // ceil(50000/256)

typedef __attribute__((ext_vector_type(8))) short bf16x8;
typedef __attribute__((ext_vector_type(4))) float f32x4;

__device__ __forceinline__ ushort bf16_rne(float f) {
    union { float f; unsigned u; } v; v.f = f;
    unsigned r = v.u + 0x7FFF + ((v.u >> 16) & 1);
    return (ushort)(r >> 16);
}
__device__ __forceinline__ float bf16_to_f(ushort h) {
    union { unsigned u; float f; } v; v.u = ((unsigned)h) << 16;
    return v.f;
}

// ---------------- CSR build ----------------

__global__ void k_count(const int* __restrict__ tgt, int* __restrict__ counts) {
    int e = blockIdx.x * blockDim.x + threadIdx.x;
    if (e < NE) atomicAdd(&counts[tgt[e]], 1);
}

__global__ void k_scan1(const int* __restrict__ counts, int* __restrict__ bsum) {
    int i = blockIdx.x * 256 + threadIdx.x;
    int v = (i < NN) ? counts[i] : 0;
    #pragma unroll
    for (int off = 32; off; off >>= 1) v += __shfl_down(v, off, 64);
    __shared__ int ws4[4];
    int wave = threadIdx.x >> 6, lane = threadIdx.x & 63;
    if (lane == 0) ws4[wave] = v;
    __syncthreads();
    if (threadIdx.x == 0) bsum[blockIdx.x] = ws4[0] + ws4[1] + ws4[2] + ws4[3];
}

__global__ void k_scan2(int* __restrict__ bsum, int nb) {
    __shared__ int s[256];
    int t = threadIdx.x;
    int v = (t < nb) ? bsum[t] : 0;
    s[t] = v;
    __syncthreads();
    for (int off = 1; off < 256; off <<= 1) {
        int a = (t >= off) ? s[t - off] : 0;
        __syncthreads();
        s[t] += a;
        __syncthreads();
    }
    if (t < nb) bsum[t] = s[t] - v;  // exclusive
}

__global__ void k_scan3(const int* __restrict__ counts, const int* __restrict__ boff,
                        int* __restrict__ rowptr, int* __restrict__ cursor) {
    __shared__ int s[256];
    int t = threadIdx.x;
    int i = blockIdx.x * 256 + t;
    int v = (i < NN) ? counts[i] : 0;
    s[t] = v;
    __syncthreads();
    for (int off = 1; off < 256; off <<= 1) {
        int a = (t >= off) ? s[t - off] : 0;
        __syncthreads();
        s[t] += a;
        __syncthreads();
    }
    int excl = s[t] - v + boff[blockIdx.x];
    if (i < NN) { rowptr[i] = excl; cursor[i] = excl; }
    if (i == NN - 1) rowptr[NN] = excl + v;  // == NE
}

__global__ void k_fill(const int* __restrict__ src, const int* __restrict__ tgt,
                       int* __restrict__ cursor, int* __restrict__ csr) {
    int e = blockIdx.x * blockDim.x + threadIdx.x;
    if (e < NE) {
        int p = atomicAdd(&cursor[tgt[e]], 1);
        csr[p] = src[e];
    }
}

// ---------------- CSR gather-mean aggregation ----------------

template <int D>
__global__ void k_agg(const float* __restrict__ in, int inStride,
                      const float* __restrict__ addp, int addStride,
                      float* __restrict__ out, int outStride,
                      const int* __restrict__ rowptr, const int* __restrict__ csr) {
    constexpr int LPR = D / 4;      // lanes per row: 16 (D=64) or 32 (D=128)
    constexpr int EPW = 64 / LPR;   // edge slots per wave: 4 or 2
    int node = blockIdx.x * 4 + (threadIdx.x >> 6);
    int lane = threadIdx.x & 63;
    if (node >= NN) return;
    int sub = lane / LPR;           // edge slot
    int li  = lane % LPR;           // float4 index within row
    int r0 = rowptr[node], r1 = rowptr[node + 1];

    float4 a0 = make_float4(0.f, 0.f, 0.f, 0.f);
    float4 a1 = make_float4(0.f, 0.f, 0.f, 0.f);
    int e0 = r0 + sub;
    int e1 = e0 + EPW;
    int i0 = (e0 < r1) ? csr[e0] : 0;
    int i1 = (e1 < r1) ? csr[e1] : 0;
    while (e1 < r1) {
        int e0n = e0 + 2 * EPW, e1n = e1 + 2 * EPW;
        int i0n = (e0n < r1) ? csr[e0n] : 0;
        int i1n = (e1n < r1) ? csr[e1n] : 0;
        float4 v0 = ((const float4*)(in + (size_t)i0 * inStride))[li];
        float4 v1 = ((const float4*)(in + (size_t)i1 * inStride))[li];
        a0.x += v0.x; a0.y += v0.y; a0.z += v0.z; a0.w += v0.w;
        a1.x += v1.x; a1.y += v1.y; a1.z += v1.z; a1.w += v1.w;
        e0 = e0n; e1 = e1n; i0 = i0n; i1 = i1n;
    }
    if (e0 < r1) {
        float4 v0 = ((const float4*)(in + (size_t)i0 * inStride))[li];
        a0.x += v0.x; a0.y += v0.y; a0.z += v0.z; a0.w += v0.w;
    }
    a0.x += a1.x; a0.y += a1.y; a0.z += a1.z; a0.w += a1.w;
    #pragma unroll
    for (int off = LPR; off < 64; off <<= 1) {
        a0.x += __shfl_xor(a0.x, off, 64);
        a0.y += __shfl_xor(a0.y, off, 64);
        a0.z += __shfl_xor(a0.z, off, 64);
        a0.w += __shfl_xor(a0.w, off, 64);
    }
    if (sub == 0) {
        float inv = 1.0f / fmaxf((float)(r1 - r0), 1.0f);
        a0.x *= inv; a0.y *= inv; a0.z *= inv; a0.w *= inv;
        if (addp) {
            float4 a = *(const float4*)&addp[(size_t)node * addStride + li * 4];
            a0.x += a.x; a0.y += a.y; a0.z += a.z; a0.w += a.w;
        }
        *(float4*)&out[(size_t)node * outStride + li * 4] = a0;
    }
}

// ---------------- weight pre-split (hi/lo bf16, chunk-contiguous) ----------------
// Logical W[K][128] (KCAT: rows stacked [W1;W2]; NCAT: cols [W1|W2]).
// Output layout: hi/lo[(k/32)*128*32 + col*32 + (k%32)] -> staging in k_mgemm is
// a pure coalesced copy (thread t copies ushorts tid*16..+15 of each chunk).

template <int K, int KA, int NCAT>
__global__ void k_wsplit(const float* __restrict__ W1, const float* __restrict__ W2,
                         ushort* __restrict__ hi, ushort* __restrict__ lo) {
    int id = blockIdx.x * 256 + threadIdx.x;
    if (id >= 128 * K) return;
    int col = id / K, k = id - col * K;
    float v;
    if constexpr (NCAT) {
        v = (col < 64) ? W1[(size_t)k * 64 + col] : W2[(size_t)k * 64 + (col - 64)];
    } else {
        v = (k < KA) ? W1[(size_t)k * 128 + col] : W2[(size_t)(k - KA) * 128 + col];
    }
    ushort h = bf16_rne(v);
    ushort l = bf16_rne(v - bf16_to_f(h));
    size_t dst = (size_t)((k >> 5) * 128 + col) * 32 + (k & 31);
    hi[dst] = h; lo[dst] = l;
}

// ---------------- MFMA GEMM (bf16x3 split = fp32 accuracy) ----------------
// out[M x 128] = In[M x K] @ W[K x 128] (+bias, relu).
// C = Ah@Wh + Ah@Wl + Al@Wh  (AlWl ~2^-16 rel, dropped).
// Block: 256 thr = 4 waves, 64 rows (wave = 1 row-tile x 8 col-tiles) ->
// 782 blocks (~3/CU, 12 waves/CU). W comes PRE-SPLIT: staging = pure copy.
// LDS [128 col][40 pad] ushort rows (80B, 16B-aligned b128 reads, 2-way banks).
// MFMA layouts (m89-verified C/D): A[j]=A[l&15][(l>>4)*8+j],
// B[j]=B[(l>>4)*8+j][l&15], D[j]=C[(l>>4)*4+j][l&15].

template <int K, int KA, int NCAT, int RELU>
__global__ void k_mgemm(const float* __restrict__ inA, const float* __restrict__ inB,
                        const ushort* __restrict__ Whi, const ushort* __restrict__ Wlo,
                        const float* __restrict__ bias, float* __restrict__ out) {
    constexpr int KB = K - KA;
    __shared__ ushort sWh[128][40];
    __shared__ ushort sWl[128][40];

    int tid = threadIdx.x;
    int wave = tid >> 6, lane = tid & 63;
    int lr  = lane & 15;          // row (A) / col (B,D) within tile
    int kg4 = lane >> 4;          // k-group 0..3
    int rbase = blockIdx.x * 64 + wave * 16;
    int row = min(rbase + lr, NN - 1);

    int scol = tid >> 1;          // staging dest col 0..127
    int skk  = (tid & 1) * 16;    // staging dest k-offset 0/16

    f32x4 acc[8];
    #pragma unroll
    for (int ct = 0; ct < 8; ct++) acc[ct] = (f32x4){0.f, 0.f, 0.f, 0.f};

    for (int k0 = 0, chunk = 0; k0 < K; k0 += 32, chunk++) {
        // ---- stage W chunk: pure coalesced copy (16 ushorts hi + 16 lo / thread) ----
        {
            size_t base = (size_t)chunk * 4096 + tid * 16;  // 4096 = 128*32
            bf16x8 h0 = *(const bf16x8*)(Whi + base);
            bf16x8 h1 = *(const bf16x8*)(Whi + base + 8);
            bf16x8 l0 = *(const bf16x8*)(Wlo + base);
            bf16x8 l1 = *(const bf16x8*)(Wlo + base + 8);
            *(bf16x8*)&sWh[scol][skk]     = h0;
            *(bf16x8*)&sWh[scol][skk + 8] = h1;
            *(bf16x8*)&sWl[scol][skk]     = l0;
            *(bf16x8*)&sWl[scol][skk + 8] = l1;
        }
        __syncthreads();

        // ---- A-frag (hi/lo) direct from global ----
        bf16x8 ah, al;
        {
            int kg2 = k0 + kg4 * 8;
            float4 v0, v1;
            if constexpr (NCAT) {
                v0 = *(const float4*)&inA[(size_t)row * K + kg2];
                v1 = *(const float4*)&inA[(size_t)row * K + kg2 + 4];
            } else {
                if (kg2 < KA) v0 = *(const float4*)&inA[(size_t)row * KA + kg2];
                else          v0 = *(const float4*)&inB[(size_t)row * KB + (kg2 - KA)];
                if (kg2 + 4 < KA) v1 = *(const float4*)&inA[(size_t)row * KA + kg2 + 4];
                else              v1 = *(const float4*)&inB[(size_t)row * KB + (kg2 + 4 - KA)];
            }
            float av[8] = {v0.x, v0.y, v0.z, v0.w, v1.x, v1.y, v1.z, v1.w};
            #pragma unroll
            for (int j = 0; j < 8; j++) {
                ushort h = bf16_rne(av[j]);
                ushort l = bf16_rne(av[j] - bf16_to_f(h));
                ah[j] = (short)h;
                al[j] = (short)l;
            }
        }

        // ---- MFMA over 8 col-tiles ----
        #pragma unroll
        for (int ct = 0; ct < 8; ct++) {
            bf16x8 bh = *(const bf16x8*)&sWh[ct * 16 + lr][kg4 * 8];
            bf16x8 bl = *(const bf16x8*)&sWl[ct * 16 + lr][kg4 * 8];
            acc[ct] = __builtin_amdgcn_mfma_f32_16x16x32_bf16(ah, bh, acc[ct], 0, 0, 0);
            acc[ct] = __builtin_amdgcn_mfma_f32_16x16x32_bf16(ah, bl, acc[ct], 0, 0, 0);
            acc[ct] = __builtin_amdgcn_mfma_f32_16x16x32_bf16(al, bh, acc[ct], 0, 0, 0);
        }
        __syncthreads();
    }

    // ---- epilogue: bias (+ReLU), store ----
    float bc[8];
    #pragma unroll
    for (int ct = 0; ct < 8; ct++) {
        int c = ct * 16 + lr;
        if constexpr (NCAT) bc[ct] = (c < 64) ? 0.f : bias[c - 64];
        else bc[ct] = bias[c];
    }
    #pragma unroll
    for (int j = 0; j < 4; j++) {
        int n = rbase + kg4 * 4 + j;
        if (n < NN) {
            float* orow = &out[(size_t)n * 128 + lr];
            #pragma unroll
            for (int ct = 0; ct < 8; ct++) {
                float v = acc[ct][j] + bc[ct];
                if (RELU) v = fmaxf(v, 0.f);
                orow[ct * 16] = v;
            }
        }
    }
}

// ---------------- decode ----------------
// 8 label-edges per wave: 4 slots x 16 lanes x float4, 2 edges per slot.

__global__ void k_decode(const int* __restrict__ eli, const float* __restrict__ z,
                         float* __restrict__ out) {
    int w = blockIdx.x * 4 + (threadIdx.x >> 6);
    int lane = threadIdx.x & 63;
    int sub = lane >> 4, li = lane & 15;
    int e0 = w * 8 + sub;
    int e1 = e0 + 4;
    float s0 = 0.f, s1 = 0.f;
    if (e0 < NL) {
        int a = eli[e0], b = eli[NL + e0];
        float4 va = *(const float4*)&z[(size_t)a * 64 + li * 4];
        float4 vb = *(const float4*)&z[(size_t)b * 64 + li * 4];
        s0 = va.x * vb.x + va.y * vb.y + va.z * vb.z + va.w * vb.w;
    }
    if (e1 < NL) {
        int a = eli[e1], b = eli[NL + e1];
        float4 va = *(const float4*)&z[(size_t)a * 64 + li * 4];
        float4 vb = *(const float4*)&z[(size_t)b * 64 + li * 4];
        s1 = va.x * vb.x + va.y * vb.y + va.z * vb.z + va.w * vb.w;
    }
    #pragma unroll
    for (int off = 1; off < 16; off <<= 1) {
        s0 += __shfl_xor(s0, off, 64);
        s1 += __shfl_xor(s1, off, 64);
    }
    if (li == 0) {
        if (e0 < NL) out[e0] = s0;
        if (e1 < NL) out[e1] = s1;
    }
}

// ---------------- launch ----------------

extern "C" void kernel_launch(void* const* d_in, const int* in_sizes, int n_in,
                              void* d_out, int out_size, void* d_ws, size_t ws_size,
                              hipStream_t stream) {
    const float* x   = (const float*)d_in[0];
    const int*   edge = (const int*)d_in[1];   // [2, NE]
    const int*   eli  = (const int*)d_in[2];   // [2, NL]
    const float* Wl1 = (const float*)d_in[3];
    const float* Wr1 = (const float*)d_in[4];
    const float* b1  = (const float*)d_in[5];
    const float* Wl2 = (const float*)d_in[6];
    const float* Wr2 = (const float*)d_in[7];
    const float* b2  = (const float*)d_in[8];
    const float* Wl3 = (const float*)d_in[9];
    const float* Wr3 = (const float*)d_in[10];
    const float* b3  = (const float*)d_in[11];
    float* out = (float*)d_out;

    char* w = (char*)d_ws;
    auto carve = [&](size_t bytes) {
        char* p = w;
        w += (bytes + 255) & ~(size_t)255;
        return p;
    };
    int*    rowptr = (int*)carve((NN + 1) * sizeof(int));
    int*    cursor = (int*)carve(NN * sizeof(int));        // doubles as counts
    int*    csr    = (int*)carve(NE * sizeof(int));
    int*    bsum   = (int*)carve(256 * sizeof(int));
    float*  M      = (float*)carve((size_t)NN * 64 * sizeof(float));   // mean1, later z
    float*  A      = (float*)carve((size_t)NN * 128 * sizeof(float));  // h1
    float*  B      = (float*)carve((size_t)NN * 128 * sizeof(float));  // mean2, later pq
    float*  C      = (float*)carve((size_t)NN * 128 * sizeof(float));  // h2
    ushort* W1h    = (ushort*)carve(128 * 128 * sizeof(ushort));
    ushort* W1l    = (ushort*)carve(128 * 128 * sizeof(ushort));
    ushort* W2h    = (ushort*)carve(128 * 256 * sizeof(ushort));
    ushort* W2l    = (ushort*)carve(128 * 256 * sizeof(ushort));
    ushort* W3h    = (ushort*)carve(128 * 128 * sizeof(ushort));
    ushort* W3l    = (ushort*)carve(128 * 128 * sizeof(ushort));

    const int* src = edge;
    const int* tgt = edge + NE;

    // weight pre-split (independent of CSR; stream-serialized)
    k_wsplit<128, 64, 0><<<64, 256, 0, stream>>>(Wl1, Wr1, W1h, W1l);
    k_wsplit<256, 128, 0><<<128, 256, 0, stream>>>(Wl2, Wr2, W2h, W2l);
    k_wsplit<128, 128, 1><<<64, 256, 0, stream>>>(Wl3, Wr3, W3h, W3l);

    hipMemsetAsync(cursor, 0, NN * sizeof(int), stream);
    k_count<<<(NE + 255) / 256, 256, 0, stream>>>(tgt, cursor);
    k_scan1<<<NB_SCAN, 256, 0, stream>>>(cursor, bsum);
    k_scan2<<<1, 256, 0, stream>>>(bsum, NB_SCAN);
    k_scan3<<<NB_SCAN, 256, 0, stream>>>(cursor, bsum, rowptr, cursor);
    k_fill<<<(NE + 255) / 256, 256, 0, stream>>>(src, tgt, cursor, csr);

    // layer 1: mean1 = mean(x); h1 = relu([mean1|x] @ [Wl1;Wr1] + b1)
    k_agg<64><<<(NN + 3) / 4, 256, 0, stream>>>(x, 64, nullptr, 0, M, 64, rowptr, csr);
    k_mgemm<128, 64, 0, 1><<<(NN + 63) / 64, 256, 0, stream>>>(M, x, W1h, W1l, b1, A);

    // layer 2: mean2 = mean(h1); h2 = relu([mean2|h1] @ [Wl2;Wr2] + b2)
    k_agg<128><<<(NN + 3) / 4, 256, 0, stream>>>(A, 128, nullptr, 0, B, 128, rowptr, csr);
    k_mgemm<256, 128, 0, 1><<<(NN + 63) / 64, 256, 0, stream>>>(B, A, W2h, W2l, b2, C);

    // layer 3 (GEMM first, then scatter 64-wide): pq = h2 @ [Wl3 | Wr3]; q gets b3
    k_mgemm<128, 128, 1, 0><<<(NN + 63) / 64, 256, 0, stream>>>(C, nullptr, W3h, W3l, b3, B);
    // z = scatter_mean(p) + q
    k_agg<64><<<(NN + 3) / 4, 256, 0, stream>>>(B, 128, B + 64, 128, M, 64, rowptr, csr);

    // decode: out[l] = dot(z[a], z[b])
    k_decode<<<(NL + 31) / 32, 256, 0, stream>>>(eli, M, out);
}

// Round 11
// 227.883 us; speedup vs baseline: 2.5042x; 1.2982x over previous
//
#include <hip/hip_runtime.h>

#define NN 50000
#define NE 800000
#define NL 200000
#define NB_SCAN 196  // ceil(50000/256)

typedef __attribute__((ext_vector_type(8))) short bf16x8;
typedef __attribute__((ext_vector_type(4))) float f32x4;

__device__ __forceinline__ ushort bf16_rne(float f) {
    union { float f; unsigned u; } v; v.f = f;
    unsigned r = v.u + 0x7FFF + ((v.u >> 16) & 1);
    return (ushort)(r >> 16);
}
__device__ __forceinline__ float bf16_to_f(ushort h) {
    union { unsigned u; float f; } v; v.u = ((unsigned)h) << 16;
    return v.f;
}
__device__ __forceinline__ float lo_f(unsigned u) {
    union { unsigned u; float f; } v; v.u = u << 16;
    return v.f;
}
__device__ __forceinline__ float hi_f(unsigned u) {
    union { unsigned u; float f; } v; v.u = u & 0xffff0000u;
    return v.f;
}

// ---------------- CSR build ----------------
// count: rank[e] = old counter value (edge's slot within its target row).
// fill is then atomic-free: csr[rowptr[tgt]+rank] = src.

__global__ void k_count(const int* __restrict__ tgt, int* __restrict__ counts,
                        int* __restrict__ rank) {
    int e = blockIdx.x * blockDim.x + threadIdx.x;
    if (e < NE) rank[e] = atomicAdd(&counts[tgt[e]], 1);
}

__global__ void k_scan1(const int* __restrict__ counts, int* __restrict__ bsum) {
    int i = blockIdx.x * 256 + threadIdx.x;
    int v = (i < NN) ? counts[i] : 0;
    #pragma unroll
    for (int off = 32; off; off >>= 1) v += __shfl_down(v, off, 64);
    __shared__ int ws4[4];
    int wave = threadIdx.x >> 6, lane = threadIdx.x & 63;
    if (lane == 0) ws4[wave] = v;
    __syncthreads();
    if (threadIdx.x == 0) bsum[blockIdx.x] = ws4[0] + ws4[1] + ws4[2] + ws4[3];
}

__global__ void k_scan2(int* __restrict__ bsum, int nb) {
    __shared__ int s[256];
    int t = threadIdx.x;
    int v = (t < nb) ? bsum[t] : 0;
    s[t] = v;
    __syncthreads();
    for (int off = 1; off < 256; off <<= 1) {
        int a = (t >= off) ? s[t - off] : 0;
        __syncthreads();
        s[t] += a;
        __syncthreads();
    }
    if (t < nb) bsum[t] = s[t] - v;  // exclusive
}

__global__ void k_scan3(const int* __restrict__ counts, const int* __restrict__ boff,
                        int* __restrict__ rowptr) {
    __shared__ int s[256];
    int t = threadIdx.x;
    int i = blockIdx.x * 256 + t;
    int v = (i < NN) ? counts[i] : 0;
    s[t] = v;
    __syncthreads();
    for (int off = 1; off < 256; off <<= 1) {
        int a = (t >= off) ? s[t - off] : 0;
        __syncthreads();
        s[t] += a;
        __syncthreads();
    }
    int excl = s[t] - v + boff[blockIdx.x];
    if (i < NN) rowptr[i] = excl;
    if (i == NN - 1) rowptr[NN] = excl + v;  // == NE
}

__global__ void k_fill(const int* __restrict__ src, const int* __restrict__ tgt,
                       const int* __restrict__ rowptr, const int* __restrict__ rank,
                       int* __restrict__ csr) {
    int e = blockIdx.x * blockDim.x + threadIdx.x;
    if (e < NE) csr[rowptr[tgt[e]] + rank[e]] = src[e];
}

// ---------------- x -> bf16 cast ----------------

__global__ void k_xcast(const float* __restrict__ x, ushort* __restrict__ xb, int n8) {
    int i = blockIdx.x * 256 + threadIdx.x;
    if (i >= n8) return;
    float4 v0 = *(const float4*)&x[i * 8];
    float4 v1 = *(const float4*)&x[i * 8 + 4];
    ushort h[8] = {bf16_rne(v0.x), bf16_rne(v0.y), bf16_rne(v0.z), bf16_rne(v0.w),
                   bf16_rne(v1.x), bf16_rne(v1.y), bf16_rne(v1.z), bf16_rne(v1.w)};
    *(bf16x8*)&xb[i * 8] = *(bf16x8*)h;
}

// ---------------- CSR gather-mean aggregation (bf16 gather) ----------------
// One wave per node; EPW edge-slots of LPR lanes, uint4 (8 bf16) per lane.
// Two interleaved streams per slot + prefetched csr indices. fp32 accumulate;
// optional fp32 addp; fp32 output.

template <int D>
__global__ void k_aggb(const ushort* __restrict__ in,
                       const float* __restrict__ addp, int addStride,
                       float* __restrict__ out, int outStride,
                       const int* __restrict__ rowptr, const int* __restrict__ csr) {
    constexpr int LPR = D / 8;      // lanes per row: 8 (D=64) or 16 (D=128)
    constexpr int EPW = 64 / LPR;   // edge slots: 8 or 4
    int node = blockIdx.x * 4 + (threadIdx.x >> 6);
    int lane = threadIdx.x & 63;
    if (node >= NN) return;
    int sub = lane / LPR;
    int li  = lane % LPR;           // 8-elem group within row
    int r0 = rowptr[node], r1 = rowptr[node + 1];

    float a[8] = {0.f, 0.f, 0.f, 0.f, 0.f, 0.f, 0.f, 0.f};
    float b[8] = {0.f, 0.f, 0.f, 0.f, 0.f, 0.f, 0.f, 0.f};
    int e0 = r0 + sub;
    int e1 = e0 + EPW;
    int i0 = (e0 < r1) ? csr[e0] : 0;
    int i1 = (e1 < r1) ? csr[e1] : 0;
    while (e1 < r1) {
        int e0n = e0 + 2 * EPW, e1n = e1 + 2 * EPW;
        int i0n = (e0n < r1) ? csr[e0n] : 0;
        int i1n = (e1n < r1) ? csr[e1n] : 0;
        uint4 v0 = *(const uint4*)(in + (size_t)i0 * D + li * 8);
        uint4 v1 = *(const uint4*)(in + (size_t)i1 * D + li * 8);
        a[0] += lo_f(v0.x); a[1] += hi_f(v0.x); a[2] += lo_f(v0.y); a[3] += hi_f(v0.y);
        a[4] += lo_f(v0.z); a[5] += hi_f(v0.z); a[6] += lo_f(v0.w); a[7] += hi_f(v0.w);
        b[0] += lo_f(v1.x); b[1] += hi_f(v1.x); b[2] += lo_f(v1.y); b[3] += hi_f(v1.y);
        b[4] += lo_f(v1.z); b[5] += hi_f(v1.z); b[6] += lo_f(v1.w); b[7] += hi_f(v1.w);
        e0 = e0n; e1 = e1n; i0 = i0n; i1 = i1n;
    }
    if (e0 < r1) {
        uint4 v0 = *(const uint4*)(in + (size_t)i0 * D + li * 8);
        a[0] += lo_f(v0.x); a[1] += hi_f(v0.x); a[2] += lo_f(v0.y); a[3] += hi_f(v0.y);
        a[4] += lo_f(v0.z); a[5] += hi_f(v0.z); a[6] += lo_f(v0.w); a[7] += hi_f(v0.w);
    }
    #pragma unroll
    for (int j = 0; j < 8; j++) a[j] += b[j];
    #pragma unroll
    for (int off = LPR; off < 64; off <<= 1)
        #pragma unroll
        for (int j = 0; j < 8; j++) a[j] += __shfl_xor(a[j], off, 64);
    if (sub == 0) {
        float inv = 1.0f / fmaxf((float)(r1 - r0), 1.0f);
        #pragma unroll
        for (int j = 0; j < 8; j++) a[j] *= inv;
        if (addp) {
            float4 p0 = *(const float4*)&addp[(size_t)node * addStride + li * 8];
            float4 p1 = *(const float4*)&addp[(size_t)node * addStride + li * 8 + 4];
            a[0] += p0.x; a[1] += p0.y; a[2] += p0.z; a[3] += p0.w;
            a[4] += p1.x; a[5] += p1.y; a[6] += p1.z; a[7] += p1.w;
        }
        *(float4*)&out[(size_t)node * outStride + li * 8]     = make_float4(a[0], a[1], a[2], a[3]);
        *(float4*)&out[(size_t)node * outStride + li * 8 + 4] = make_float4(a[4], a[5], a[6], a[7]);
    }
}

// ---------------- weight pre-split (hi/lo bf16, chunk-contiguous) ----------------

template <int K, int KA, int NCAT>
__global__ void k_wsplit(const float* __restrict__ W1, const float* __restrict__ W2,
                         ushort* __restrict__ hi, ushort* __restrict__ lo) {
    int id = blockIdx.x * 256 + threadIdx.x;
    if (id >= 128 * K) return;
    int col = id / K, k = id - col * K;
    float v;
    if constexpr (NCAT) {
        v = (col < 64) ? W1[(size_t)k * 64 + col] : W2[(size_t)k * 64 + (col - 64)];
    } else {
        v = (k < KA) ? W1[(size_t)k * 128 + col] : W2[(size_t)(k - KA) * 128 + col];
    }
    ushort h = bf16_rne(v);
    ushort l = bf16_rne(v - bf16_to_f(h));
    size_t dst = (size_t)((k >> 5) * 128 + col) * 32 + (k & 31);
    hi[dst] = h; lo[dst] = l;
}

// ---------------- MFMA GEMM (bf16x3 split = fp32 accuracy) ----------------
// BFOUT: 0 = none; 1 = also write bf16 copy of all 128 cols (stride 128);
//        2 = also write bf16 copy of cols 0..63 (stride 64).

template <int K, int KA, int NCAT, int RELU, int BFOUT>
__global__ void k_mgemm(const float* __restrict__ inA, const float* __restrict__ inB,
                        const ushort* __restrict__ Whi, const ushort* __restrict__ Wlo,
                        const float* __restrict__ bias, float* __restrict__ out,
                        ushort* __restrict__ bfout) {
    constexpr int KB = K - KA;
    __shared__ ushort sWh[128][40];
    __shared__ ushort sWl[128][40];

    int tid = threadIdx.x;
    int wave = tid >> 6, lane = tid & 63;
    int lr  = lane & 15;
    int kg4 = lane >> 4;
    int rbase = blockIdx.x * 64 + wave * 16;
    int row = min(rbase + lr, NN - 1);

    int scol = tid >> 1;
    int skk  = (tid & 1) * 16;

    f32x4 acc[8];
    #pragma unroll
    for (int ct = 0; ct < 8; ct++) acc[ct] = (f32x4){0.f, 0.f, 0.f, 0.f};

    for (int k0 = 0, chunk = 0; k0 < K; k0 += 32, chunk++) {
        {
            size_t base = (size_t)chunk * 4096 + tid * 16;
            bf16x8 h0 = *(const bf16x8*)(Whi + base);
            bf16x8 h1 = *(const bf16x8*)(Whi + base + 8);
            bf16x8 l0 = *(const bf16x8*)(Wlo + base);
            bf16x8 l1 = *(const bf16x8*)(Wlo + base + 8);
            *(bf16x8*)&sWh[scol][skk]     = h0;
            *(bf16x8*)&sWh[scol][skk + 8] = h1;
            *(bf16x8*)&sWl[scol][skk]     = l0;
            *(bf16x8*)&sWl[scol][skk + 8] = l1;
        }
        __syncthreads();

        bf16x8 ah, al;
        {
            int kg2 = k0 + kg4 * 8;
            float4 v0, v1;
            if constexpr (NCAT) {
                v0 = *(const float4*)&inA[(size_t)row * K + kg2];
                v1 = *(const float4*)&inA[(size_t)row * K + kg2 + 4];
            } else {
                if (kg2 < KA) v0 = *(const float4*)&inA[(size_t)row * KA + kg2];
                else          v0 = *(const float4*)&inB[(size_t)row * KB + (kg2 - KA)];
                if (kg2 + 4 < KA) v1 = *(const float4*)&inA[(size_t)row * KA + kg2 + 4];
                else              v1 = *(const float4*)&inB[(size_t)row * KB + (kg2 + 4 - KA)];
            }
            float av[8] = {v0.x, v0.y, v0.z, v0.w, v1.x, v1.y, v1.z, v1.w};
            #pragma unroll
            for (int j = 0; j < 8; j++) {
                ushort h = bf16_rne(av[j]);
                ushort l = bf16_rne(av[j] - bf16_to_f(h));
                ah[j] = (short)h;
                al[j] = (short)l;
            }
        }

        #pragma unroll
        for (int ct = 0; ct < 8; ct++) {
            bf16x8 bh = *(const bf16x8*)&sWh[ct * 16 + lr][kg4 * 8];
            bf16x8 bl = *(const bf16x8*)&sWl[ct * 16 + lr][kg4 * 8];
            acc[ct] = __builtin_amdgcn_mfma_f32_16x16x32_bf16(ah, bh, acc[ct], 0, 0, 0);
            acc[ct] = __builtin_amdgcn_mfma_f32_16x16x32_bf16(ah, bl, acc[ct], 0, 0, 0);
            acc[ct] = __builtin_amdgcn_mfma_f32_16x16x32_bf16(al, bh, acc[ct], 0, 0, 0);
        }
        __syncthreads();
    }

    float bc[8];
    #pragma unroll
    for (int ct = 0; ct < 8; ct++) {
        int c = ct * 16 + lr;
        if constexpr (NCAT) bc[ct] = (c < 64) ? 0.f : bias[c - 64];
        else bc[ct] = bias[c];
    }
    #pragma unroll
    for (int j = 0; j < 4; j++) {
        int n = rbase + kg4 * 4 + j;
        if (n < NN) {
            float* orow = &out[(size_t)n * 128 + lr];
            #pragma unroll
            for (int ct = 0; ct < 8; ct++) {
                float v = acc[ct][j] + bc[ct];
                if (RELU) v = fmaxf(v, 0.f);
                orow[ct * 16] = v;
                if constexpr (BFOUT == 1) bfout[(size_t)n * 128 + ct * 16 + lr] = bf16_rne(v);
                if constexpr (BFOUT == 2) { if (ct < 4) bfout[(size_t)n * 64 + ct * 16 + lr] = bf16_rne(v); }
            }
        }
    }
}

// ---------------- decode ----------------

__global__ void k_decode(const int* __restrict__ eli, const float* __restrict__ z,
                         float* __restrict__ out) {
    int w = blockIdx.x * 4 + (threadIdx.x >> 6);
    int lane = threadIdx.x & 63;
    int sub = lane >> 4, li = lane & 15;
    int e0 = w * 8 + sub;
    int e1 = e0 + 4;
    float s0 = 0.f, s1 = 0.f;
    if (e0 < NL) {
        int a = eli[e0], b = eli[NL + e0];
        float4 va = *(const float4*)&z[(size_t)a * 64 + li * 4];
        float4 vb = *(const float4*)&z[(size_t)b * 64 + li * 4];
        s0 = va.x * vb.x + va.y * vb.y + va.z * vb.z + va.w * vb.w;
    }
    if (e1 < NL) {
        int a = eli[e1], b = eli[NL + e1];
        float4 va = *(const float4*)&z[(size_t)a * 64 + li * 4];
        float4 vb = *(const float4*)&z[(size_t)b * 64 + li * 4];
        s1 = va.x * vb.x + va.y * vb.y + va.z * vb.z + va.w * vb.w;
    }
    #pragma unroll
    for (int off = 1; off < 16; off <<= 1) {
        s0 += __shfl_xor(s0, off, 64);
        s1 += __shfl_xor(s1, off, 64);
    }
    if (li == 0) {
        if (e0 < NL) out[e0] = s0;
        if (e1 < NL) out[e1] = s1;
    }
}

// ---------------- launch ----------------

extern "C" void kernel_launch(void* const* d_in, const int* in_sizes, int n_in,
                              void* d_out, int out_size, void* d_ws, size_t ws_size,
                              hipStream_t stream) {
    const float* x   = (const float*)d_in[0];
    const int*   edge = (const int*)d_in[1];   // [2, NE]
    const int*   eli  = (const int*)d_in[2];   // [2, NL]
    const float* Wl1 = (const float*)d_in[3];
    const float* Wr1 = (const float*)d_in[4];
    const float* b1  = (const float*)d_in[5];
    const float* Wl2 = (const float*)d_in[6];
    const float* Wr2 = (const float*)d_in[7];
    const float* b2  = (const float*)d_in[8];
    const float* Wl3 = (const float*)d_in[9];
    const float* Wr3 = (const float*)d_in[10];
    const float* b3  = (const float*)d_in[11];
    float* out = (float*)d_out;

    char* w = (char*)d_ws;
    auto carve = [&](size_t bytes) {
        char* p = w;
        w += (bytes + 255) & ~(size_t)255;
        return p;
    };
    int*    rowptr = (int*)carve((NN + 1) * sizeof(int));
    int*    counts = (int*)carve(NN * sizeof(int));
    int*    rank   = (int*)carve(NE * sizeof(int));
    int*    csr    = (int*)carve(NE * sizeof(int));
    int*    bsum   = (int*)carve(256 * sizeof(int));
    float*  M      = (float*)carve((size_t)NN * 64 * sizeof(float));   // mean1, later z
    float*  A      = (float*)carve((size_t)NN * 128 * sizeof(float));  // h1
    float*  B      = (float*)carve((size_t)NN * 128 * sizeof(float));  // mean2, later pq
    float*  C      = (float*)carve((size_t)NN * 128 * sizeof(float));  // h2
    ushort* xb     = (ushort*)carve((size_t)NN * 64 * sizeof(ushort));  // bf16 x
    ushort* h1b    = (ushort*)carve((size_t)NN * 128 * sizeof(ushort)); // bf16 h1
    ushort* pb     = (ushort*)carve((size_t)NN * 64 * sizeof(ushort));  // bf16 p
    ushort* W1h    = (ushort*)carve(128 * 128 * sizeof(ushort));
    ushort* W1l    = (ushort*)carve(128 * 128 * sizeof(ushort));
    ushort* W2h    = (ushort*)carve(128 * 256 * sizeof(ushort));
    ushort* W2l    = (ushort*)carve(128 * 256 * sizeof(ushort));
    ushort* W3h    = (ushort*)carve(128 * 128 * sizeof(ushort));
    ushort* W3l    = (ushort*)carve(128 * 128 * sizeof(ushort));

    const int* src = edge;
    const int* tgt = edge + NE;

    // prep: weight pre-split + x bf16 cast
    k_wsplit<128, 64, 0><<<64, 256, 0, stream>>>(Wl1, Wr1, W1h, W1l);
    k_wsplit<256, 128, 0><<<128, 256, 0, stream>>>(Wl2, Wr2, W2h, W2l);
    k_wsplit<128, 128, 1><<<64, 256, 0, stream>>>(Wl3, Wr3, W3h, W3l);
    k_xcast<<<(NN * 8 + 255) / 256, 256, 0, stream>>>(x, xb, NN * 8);

    // CSR build
    hipMemsetAsync(counts, 0, NN * sizeof(int), stream);
    k_count<<<(NE + 255) / 256, 256, 0, stream>>>(tgt, counts, rank);
    k_scan1<<<NB_SCAN, 256, 0, stream>>>(counts, bsum);
    k_scan2<<<1, 256, 0, stream>>>(bsum, NB_SCAN);
    k_scan3<<<NB_SCAN, 256, 0, stream>>>(counts, bsum, rowptr);
    k_fill<<<(NE + 255) / 256, 256, 0, stream>>>(src, tgt, rowptr, rank, csr);

    // layer 1: mean1 = mean(x); h1 = relu([mean1|x] @ [Wl1;Wr1] + b1)  (+h1 bf16 copy)
    k_aggb<64><<<(NN + 3) / 4, 256, 0, stream>>>(xb, nullptr, 0, M, 64, rowptr, csr);
    k_mgemm<128, 64, 0, 1, 1><<<(NN + 63) / 64, 256, 0, stream>>>(M, x, W1h, W1l, b1, A, h1b);

    // layer 2: mean2 = mean(h1); h2 = relu([mean2|h1] @ [Wl2;Wr2] + b2)
    k_aggb<128><<<(NN + 3) / 4, 256, 0, stream>>>(h1b, nullptr, 0, B, 128, rowptr, csr);
    k_mgemm<256, 128, 0, 1, 0><<<(NN + 63) / 64, 256, 0, stream>>>(B, A, W2h, W2l, b2, C, nullptr);

    // layer 3: pq = h2 @ [Wl3 | Wr3] (+p bf16 copy); z = scatter_mean(p) + q
    k_mgemm<128, 128, 1, 0, 2><<<(NN + 63) / 64, 256, 0, stream>>>(C, nullptr, W3h, W3l, b3, B, pb);
    k_aggb<64><<<(NN + 3) / 4, 256, 0, stream>>>(pb, B + 64, 128, M, 64, rowptr, csr);

    // decode: out[l] = dot(z[a], z[b])
    k_decode<<<(NL + 31) / 32, 256, 0, stream>>>(eli, M, out);
}

// Round 12
// 226.548 us; speedup vs baseline: 2.5189x; 1.0059x over previous
//
#include <hip/hip_runtime.h>

#define NN 50000
#define NE 800000
#define NL 200000
#define NB_SCAN 196  // ceil(50000/256)

typedef __attribute__((ext_vector_type(8))) short bf16x8;
typedef __attribute__((ext_vector_type(4))) float f32x4;

__device__ __forceinline__ ushort bf16_rne(float f) {
    union { float f; unsigned u; } v; v.f = f;
    unsigned r = v.u + 0x7FFF + ((v.u >> 16) & 1);
    return (ushort)(r >> 16);
}
__device__ __forceinline__ float bf16_to_f(ushort h) {
    union { unsigned u; float f; } v; v.u = ((unsigned)h) << 16;
    return v.f;
}
__device__ __forceinline__ float lo_f(unsigned u) {
    union { unsigned u; float f; } v; v.u = u << 16;
    return v.f;
}
__device__ __forceinline__ float hi_f(unsigned u) {
    union { unsigned u; float f; } v; v.u = u & 0xffff0000u;
    return v.f;
}

// ---------------- CSR build ----------------
// count: rank[e] = old counter value; fill is then atomic-free.

__global__ void k_count(const int* __restrict__ tgt, int* __restrict__ counts,
                        int* __restrict__ rank) {
    int e = blockIdx.x * blockDim.x + threadIdx.x;
    if (e < NE) rank[e] = atomicAdd(&counts[tgt[e]], 1);
}

__global__ void k_scan1(const int* __restrict__ counts, int* __restrict__ bsum) {
    int i = blockIdx.x * 256 + threadIdx.x;
    int v = (i < NN) ? counts[i] : 0;
    #pragma unroll
    for (int off = 32; off; off >>= 1) v += __shfl_down(v, off, 64);
    __shared__ int ws4[4];
    int wave = threadIdx.x >> 6, lane = threadIdx.x & 63;
    if (lane == 0) ws4[wave] = v;
    __syncthreads();
    if (threadIdx.x == 0) bsum[blockIdx.x] = ws4[0] + ws4[1] + ws4[2] + ws4[3];
}

__global__ void k_scan2(int* __restrict__ bsum, int nb) {
    __shared__ int s[256];
    int t = threadIdx.x;
    int v = (t < nb) ? bsum[t] : 0;
    s[t] = v;
    __syncthreads();
    for (int off = 1; off < 256; off <<= 1) {
        int a = (t >= off) ? s[t - off] : 0;
        __syncthreads();
        s[t] += a;
        __syncthreads();
    }
    if (t < nb) bsum[t] = s[t] - v;  // exclusive
}

__global__ void k_scan3(const int* __restrict__ counts, const int* __restrict__ boff,
                        int* __restrict__ rowptr) {
    __shared__ int s[256];
    int t = threadIdx.x;
    int i = blockIdx.x * 256 + t;
    int v = (i < NN) ? counts[i] : 0;
    s[t] = v;
    __syncthreads();
    for (int off = 1; off < 256; off <<= 1) {
        int a = (t >= off) ? s[t - off] : 0;
        __syncthreads();
        s[t] += a;
        __syncthreads();
    }
    int excl = s[t] - v + boff[blockIdx.x];
    if (i < NN) rowptr[i] = excl;
    if (i == NN - 1) rowptr[NN] = excl + v;  // == NE
}

__global__ void k_fill(const int* __restrict__ src, const int* __restrict__ tgt,
                       const int* __restrict__ rowptr, const int* __restrict__ rank,
                       int* __restrict__ csr) {
    int e = blockIdx.x * blockDim.x + threadIdx.x;
    if (e < NE) csr[rowptr[tgt[e]] + rank[e]] = src[e];
}

// ---------------- x -> bf16 cast ----------------

__global__ void k_xcast(const float* __restrict__ x, ushort* __restrict__ xb, int n8) {
    int i = blockIdx.x * 256 + threadIdx.x;
    if (i >= n8) return;
    float4 v0 = *(const float4*)&x[i * 8];
    float4 v1 = *(const float4*)&x[i * 8 + 4];
    ushort h[8] = {bf16_rne(v0.x), bf16_rne(v0.y), bf16_rne(v0.z), bf16_rne(v0.w),
                   bf16_rne(v1.x), bf16_rne(v1.y), bf16_rne(v1.z), bf16_rne(v1.w)};
    *(bf16x8*)&xb[i * 8] = *(bf16x8*)h;
}

// ---------------- CSR gather-mean aggregation (bf16 gather) ----------------

template <int D>
__global__ void k_aggb(const ushort* __restrict__ in,
                       const float* __restrict__ addp, int addStride,
                       float* __restrict__ out, int outStride,
                       const int* __restrict__ rowptr, const int* __restrict__ csr) {
    constexpr int LPR = D / 8;      // lanes per row: 8 (D=64) or 16 (D=128)
    constexpr int EPW = 64 / LPR;   // edge slots: 8 or 4
    int node = blockIdx.x * 4 + (threadIdx.x >> 6);
    int lane = threadIdx.x & 63;
    if (node >= NN) return;
    int sub = lane / LPR;
    int li  = lane % LPR;           // 8-elem group within row
    int r0 = rowptr[node], r1 = rowptr[node + 1];

    float a[8] = {0.f, 0.f, 0.f, 0.f, 0.f, 0.f, 0.f, 0.f};
    float b[8] = {0.f, 0.f, 0.f, 0.f, 0.f, 0.f, 0.f, 0.f};
    int e0 = r0 + sub;
    int e1 = e0 + EPW;
    int i0 = (e0 < r1) ? csr[e0] : 0;
    int i1 = (e1 < r1) ? csr[e1] : 0;
    while (e1 < r1) {
        int e0n = e0 + 2 * EPW, e1n = e1 + 2 * EPW;
        int i0n = (e0n < r1) ? csr[e0n] : 0;
        int i1n = (e1n < r1) ? csr[e1n] : 0;
        uint4 v0 = *(const uint4*)(in + (size_t)i0 * D + li * 8);
        uint4 v1 = *(const uint4*)(in + (size_t)i1 * D + li * 8);
        a[0] += lo_f(v0.x); a[1] += hi_f(v0.x); a[2] += lo_f(v0.y); a[3] += hi_f(v0.y);
        a[4] += lo_f(v0.z); a[5] += hi_f(v0.z); a[6] += lo_f(v0.w); a[7] += hi_f(v0.w);
        b[0] += lo_f(v1.x); b[1] += hi_f(v1.x); b[2] += lo_f(v1.y); b[3] += hi_f(v1.y);
        b[4] += lo_f(v1.z); b[5] += hi_f(v1.z); b[6] += lo_f(v1.w); b[7] += hi_f(v1.w);
        e0 = e0n; e1 = e1n; i0 = i0n; i1 = i1n;
    }
    if (e0 < r1) {
        uint4 v0 = *(const uint4*)(in + (size_t)i0 * D + li * 8);
        a[0] += lo_f(v0.x); a[1] += hi_f(v0.x); a[2] += lo_f(v0.y); a[3] += hi_f(v0.y);
        a[4] += lo_f(v0.z); a[5] += hi_f(v0.z); a[6] += lo_f(v0.w); a[7] += hi_f(v0.w);
    }
    #pragma unroll
    for (int j = 0; j < 8; j++) a[j] += b[j];
    #pragma unroll
    for (int off = LPR; off < 64; off <<= 1)
        #pragma unroll
        for (int j = 0; j < 8; j++) a[j] += __shfl_xor(a[j], off, 64);
    if (sub == 0) {
        float inv = 1.0f / fmaxf((float)(r1 - r0), 1.0f);
        #pragma unroll
        for (int j = 0; j < 8; j++) a[j] *= inv;
        if (addp) {
            float4 p0 = *(const float4*)&addp[(size_t)node * addStride + li * 8];
            float4 p1 = *(const float4*)&addp[(size_t)node * addStride + li * 8 + 4];
            a[0] += p0.x; a[1] += p0.y; a[2] += p0.z; a[3] += p0.w;
            a[4] += p1.x; a[5] += p1.y; a[6] += p1.z; a[7] += p1.w;
        }
        *(float4*)&out[(size_t)node * outStride + li * 8]     = make_float4(a[0], a[1], a[2], a[3]);
        *(float4*)&out[(size_t)node * outStride + li * 8 + 4] = make_float4(a[4], a[5], a[6], a[7]);
    }
}

// ---------------- weight pre-split: per-lane MFMA fragment layout ----------------
// frag[chunk][ct][lane][j]: B-frag for k-chunk, col-tile ct; lane = kg4*16+lr;
// element j -> W[chunk*32 + kg4*8 + j][ct*16 + lr].
// k_mgemm lane loads its 16B fragment with ONE global load (L2-resident).

template <int K, int KA, int NCAT>
__global__ void k_wsplit(const float* __restrict__ W1, const float* __restrict__ W2,
                         ushort* __restrict__ hi, ushort* __restrict__ lo) {
    int id = blockIdx.x * 256 + threadIdx.x;
    if (id >= 128 * K) return;
    int col = id / K, k = id - col * K;
    float v;
    if constexpr (NCAT) {
        v = (col < 64) ? W1[(size_t)k * 64 + col] : W2[(size_t)k * 64 + (col - 64)];
    } else {
        v = (k < KA) ? W1[(size_t)k * 128 + col] : W2[(size_t)(k - KA) * 128 + col];
    }
    ushort h = bf16_rne(v);
    ushort l = bf16_rne(v - bf16_to_f(h));
    int chunk = k >> 5, kk = k & 31;
    int kg4 = kk >> 3, j = kk & 7;
    int ct = col >> 4, lr = col & 15;
    size_t dst = ((size_t)(chunk * 8 + ct) * 64 + kg4 * 16 + lr) * 8 + j;
    hi[dst] = h; lo[dst] = l;
}

// ---------------- MFMA GEMM (bf16x3 split = fp32 accuracy) ----------------
// Barrier-free, LDS-free: W read per-lane from pre-arranged fragment buffer
// (L2-hot, one 16B load per fragment); A prefetched one chunk ahead so HBM
// latency pipelines under the 24 MFMAs of the previous chunk. Waves fully
// independent. Block: 256 thr = 4 waves x 16 rows = 64 rows.
// C = Ah@Wh + Ah@Wl + Al@Wh. MFMA layouts (m89): A[j]=A[lr][kg4*8+j],
// B[j]=B[kg4*8+j][lr], D[j]=C[kg4*4+j][lr].
// BFOUT: 1 = also write bf16 copy (stride 128); 2 = bf16 copy cols 0..63.

template <int K, int KA, int NCAT, int RELU, int BFOUT>
__global__ void k_mgemm(const float* __restrict__ inA, const float* __restrict__ inB,
                        const ushort* __restrict__ Whi, const ushort* __restrict__ Wlo,
                        const float* __restrict__ bias, float* __restrict__ out,
                        ushort* __restrict__ bfout) {
    constexpr int KB = K - KA;
    constexpr int NCH = K / 32;

    int tid = threadIdx.x;
    int wave = tid >> 6, lane = tid & 63;
    int lr  = lane & 15;
    int kg4 = lane >> 4;
    int rbase = blockIdx.x * 64 + wave * 16;
    int row = min(rbase + lr, NN - 1);

    f32x4 acc[8];
    #pragma unroll
    for (int ct = 0; ct < 8; ct++) acc[ct] = (f32x4){0.f, 0.f, 0.f, 0.f};

    auto loadA = [&](int chunk, float4& v0, float4& v1) {
        int kg2 = chunk * 32 + kg4 * 8;
        if constexpr (NCAT) {
            v0 = *(const float4*)&inA[(size_t)row * K + kg2];
            v1 = *(const float4*)&inA[(size_t)row * K + kg2 + 4];
        } else {
            if (kg2 < KA) v0 = *(const float4*)&inA[(size_t)row * KA + kg2];
            else          v0 = *(const float4*)&inB[(size_t)row * KB + (kg2 - KA)];
            if (kg2 + 4 < KA) v1 = *(const float4*)&inA[(size_t)row * KA + kg2 + 4];
            else              v1 = *(const float4*)&inB[(size_t)row * KB + (kg2 + 4 - KA)];
        }
    };

    float4 a0, a1;
    loadA(0, a0, a1);

    for (int chunk = 0; chunk < NCH; chunk++) {
        float4 n0 = make_float4(0.f, 0.f, 0.f, 0.f);
        float4 n1 = make_float4(0.f, 0.f, 0.f, 0.f);
        if (chunk + 1 < NCH) loadA(chunk + 1, n0, n1);  // prefetch next A

        bf16x8 ah, al;
        {
            float av[8] = {a0.x, a0.y, a0.z, a0.w, a1.x, a1.y, a1.z, a1.w};
            #pragma unroll
            for (int j = 0; j < 8; j++) {
                ushort h = bf16_rne(av[j]);
                ushort l = bf16_rne(av[j] - bf16_to_f(h));
                ah[j] = (short)h;
                al[j] = (short)l;
            }
        }

        const ushort* wb_h = Whi + (size_t)chunk * 4096 + (size_t)lane * 8;
        const ushort* wb_l = Wlo + (size_t)chunk * 4096 + (size_t)lane * 8;
        #pragma unroll
        for (int ct = 0; ct < 8; ct++) {
            bf16x8 bh = *(const bf16x8*)(wb_h + ct * 512);
            bf16x8 bl = *(const bf16x8*)(wb_l + ct * 512);
            acc[ct] = __builtin_amdgcn_mfma_f32_16x16x32_bf16(ah, bh, acc[ct], 0, 0, 0);
            acc[ct] = __builtin_amdgcn_mfma_f32_16x16x32_bf16(ah, bl, acc[ct], 0, 0, 0);
            acc[ct] = __builtin_amdgcn_mfma_f32_16x16x32_bf16(al, bh, acc[ct], 0, 0, 0);
        }
        a0 = n0; a1 = n1;
    }

    float bc[8];
    #pragma unroll
    for (int ct = 0; ct < 8; ct++) {
        int c = ct * 16 + lr;
        if constexpr (NCAT) bc[ct] = (c < 64) ? 0.f : bias[c - 64];
        else bc[ct] = bias[c];
    }
    #pragma unroll
    for (int j = 0; j < 4; j++) {
        int n = rbase + kg4 * 4 + j;
        if (n < NN) {
            float* orow = &out[(size_t)n * 128 + lr];
            #pragma unroll
            for (int ct = 0; ct < 8; ct++) {
                float v = acc[ct][j] + bc[ct];
                if (RELU) v = fmaxf(v, 0.f);
                orow[ct * 16] = v;
                if constexpr (BFOUT == 1) bfout[(size_t)n * 128 + ct * 16 + lr] = bf16_rne(v);
                if constexpr (BFOUT == 2) { if (ct < 4) bfout[(size_t)n * 64 + ct * 16 + lr] = bf16_rne(v); }
            }
        }
    }
}

// ---------------- decode ----------------

__global__ void k_decode(const int* __restrict__ eli, const float* __restrict__ z,
                         float* __restrict__ out) {
    int w = blockIdx.x * 4 + (threadIdx.x >> 6);
    int lane = threadIdx.x & 63;
    int sub = lane >> 4, li = lane & 15;
    int e0 = w * 8 + sub;
    int e1 = e0 + 4;
    float s0 = 0.f, s1 = 0.f;
    if (e0 < NL) {
        int a = eli[e0], b = eli[NL + e0];
        float4 va = *(const float4*)&z[(size_t)a * 64 + li * 4];
        float4 vb = *(const float4*)&z[(size_t)b * 64 + li * 4];
        s0 = va.x * vb.x + va.y * vb.y + va.z * vb.z + va.w * vb.w;
    }
    if (e1 < NL) {
        int a = eli[e1], b = eli[NL + e1];
        float4 va = *(const float4*)&z[(size_t)a * 64 + li * 4];
        float4 vb = *(const float4*)&z[(size_t)b * 64 + li * 4];
        s1 = va.x * vb.x + va.y * vb.y + va.z * vb.z + va.w * vb.w;
    }
    #pragma unroll
    for (int off = 1; off < 16; off <<= 1) {
        s0 += __shfl_xor(s0, off, 64);
        s1 += __shfl_xor(s1, off, 64);
    }
    if (li == 0) {
        if (e0 < NL) out[e0] = s0;
        if (e1 < NL) out[e1] = s1;
    }
}

// ---------------- launch ----------------

extern "C" void kernel_launch(void* const* d_in, const int* in_sizes, int n_in,
                              void* d_out, int out_size, void* d_ws, size_t ws_size,
                              hipStream_t stream) {
    const float* x   = (const float*)d_in[0];
    const int*   edge = (const int*)d_in[1];   // [2, NE]
    const int*   eli  = (const int*)d_in[2];   // [2, NL]
    const float* Wl1 = (const float*)d_in[3];
    const float* Wr1 = (const float*)d_in[4];
    const float* b1  = (const float*)d_in[5];
    const float* Wl2 = (const float*)d_in[6];
    const float* Wr2 = (const float*)d_in[7];
    const float* b2  = (const float*)d_in[8];
    const float* Wl3 = (const float*)d_in[9];
    const float* Wr3 = (const float*)d_in[10];
    const float* b3  = (const float*)d_in[11];
    float* out = (float*)d_out;

    char* w = (char*)d_ws;
    auto carve = [&](size_t bytes) {
        char* p = w;
        w += (bytes + 255) & ~(size_t)255;
        return p;
    };
    int*    rowptr = (int*)carve((NN + 1) * sizeof(int));
    int*    counts = (int*)carve(NN * sizeof(int));
    int*    rank   = (int*)carve(NE * sizeof(int));
    int*    csr    = (int*)carve(NE * sizeof(int));
    int*    bsum   = (int*)carve(256 * sizeof(int));
    float*  M      = (float*)carve((size_t)NN * 64 * sizeof(float));   // mean1, later z
    float*  A      = (float*)carve((size_t)NN * 128 * sizeof(float));  // h1
    float*  B      = (float*)carve((size_t)NN * 128 * sizeof(float));  // mean2, later pq
    float*  C      = (float*)carve((size_t)NN * 128 * sizeof(float));  // h2
    ushort* xb     = (ushort*)carve((size_t)NN * 64 * sizeof(ushort));  // bf16 x
    ushort* h1b    = (ushort*)carve((size_t)NN * 128 * sizeof(ushort)); // bf16 h1
    ushort* pb     = (ushort*)carve((size_t)NN * 64 * sizeof(ushort));  // bf16 p
    ushort* W1h    = (ushort*)carve(128 * 128 * sizeof(ushort));
    ushort* W1l    = (ushort*)carve(128 * 128 * sizeof(ushort));
    ushort* W2h    = (ushort*)carve(128 * 256 * sizeof(ushort));
    ushort* W2l    = (ushort*)carve(128 * 256 * sizeof(ushort));
    ushort* W3h    = (ushort*)carve(128 * 128 * sizeof(ushort));
    ushort* W3l    = (ushort*)carve(128 * 128 * sizeof(ushort));

    const int* src = edge;
    const int* tgt = edge + NE;

    // prep: weight pre-split (fragment layout) + x bf16 cast
    k_wsplit<128, 64, 0><<<64, 256, 0, stream>>>(Wl1, Wr1, W1h, W1l);
    k_wsplit<256, 128, 0><<<128, 256, 0, stream>>>(Wl2, Wr2, W2h, W2l);
    k_wsplit<128, 128, 1><<<64, 256, 0, stream>>>(Wl3, Wr3, W3h, W3l);
    k_xcast<<<(NN * 8 + 255) / 256, 256, 0, stream>>>(x, xb, NN * 8);

    // CSR build
    hipMemsetAsync(counts, 0, NN * sizeof(int), stream);
    k_count<<<(NE + 255) / 256, 256, 0, stream>>>(tgt, counts, rank);
    k_scan1<<<NB_SCAN, 256, 0, stream>>>(counts, bsum);
    k_scan2<<<1, 256, 0, stream>>>(bsum, NB_SCAN);
    k_scan3<<<NB_SCAN, 256, 0, stream>>>(counts, bsum, rowptr);
    k_fill<<<(NE + 255) / 256, 256, 0, stream>>>(src, tgt, rowptr, rank, csr);

    // layer 1: mean1 = mean(x); h1 = relu([mean1|x] @ [Wl1;Wr1] + b1)  (+h1 bf16 copy)
    k_aggb<64><<<(NN + 3) / 4, 256, 0, stream>>>(xb, nullptr, 0, M, 64, rowptr, csr);
    k_mgemm<128, 64, 0, 1, 1><<<(NN + 63) / 64, 256, 0, stream>>>(M, x, W1h, W1l, b1, A, h1b);

    // layer 2: mean2 = mean(h1); h2 = relu([mean2|h1] @ [Wl2;Wr2] + b2)
    k_aggb<128><<<(NN + 3) / 4, 256, 0, stream>>>(h1b, nullptr, 0, B, 128, rowptr, csr);
    k_mgemm<256, 128, 0, 1, 0><<<(NN + 63) / 64, 256, 0, stream>>>(B, A, W2h, W2l, b2, C, nullptr);

    // layer 3: pq = h2 @ [Wl3 | Wr3] (+p bf16 copy); z = scatter_mean(p) + q
    k_mgemm<128, 128, 1, 0, 2><<<(NN + 63) / 64, 256, 0, stream>>>(C, nullptr, W3h, W3l, b3, B, pb);
    k_aggb<64><<<(NN + 3) / 4, 256, 0, stream>>>(pb, B + 64, 128, M, 64, rowptr, csr);

    // decode: out[l] = dot(z[a], z[b])
    k_decode<<<(NL + 31) / 32, 256, 0, stream>>>(eli, M, out);
}

// Round 13
// 221.070 us; speedup vs baseline: 2.5814x; 1.0248x over previous
//
#include <hip/hip_runtime.h>

#define NN 50000
#define NE 800000
#define NL 200000
#define NB_SCAN 196  // ceil(50000/256)

typedef __attribute__((ext_vector_type(8))) short bf16x8;
typedef __attribute__((ext_vector_type(4))) float f32x4;

__device__ __forceinline__ ushort bf16_rne(float f) {
    union { float f; unsigned u; } v; v.f = f;
    unsigned r = v.u + 0x7FFF + ((v.u >> 16) & 1);
    return (ushort)(r >> 16);
}
__device__ __forceinline__ float bf16_to_f(ushort h) {
    union { unsigned u; float f; } v; v.u = ((unsigned)h) << 16;
    return v.f;
}
__device__ __forceinline__ float lo_f(unsigned u) {
    union { unsigned u; float f; } v; v.u = u << 16;
    return v.f;
}
__device__ __forceinline__ float hi_f(unsigned u) {
    union { unsigned u; float f; } v; v.u = u & 0xffff0000u;
    return v.f;
}

// ---------------- CSR build ----------------

__global__ void k_count(const int* __restrict__ tgt, int* __restrict__ counts,
                        int* __restrict__ rank) {
    int e = blockIdx.x * blockDim.x + threadIdx.x;
    if (e < NE) rank[e] = atomicAdd(&counts[tgt[e]], 1);
}

__global__ void k_scan1(const int* __restrict__ counts, int* __restrict__ bsum) {
    int i = blockIdx.x * 256 + threadIdx.x;
    int v = (i < NN) ? counts[i] : 0;
    #pragma unroll
    for (int off = 32; off; off >>= 1) v += __shfl_down(v, off, 64);
    __shared__ int ws4[4];
    int wave = threadIdx.x >> 6, lane = threadIdx.x & 63;
    if (lane == 0) ws4[wave] = v;
    __syncthreads();
    if (threadIdx.x == 0) bsum[blockIdx.x] = ws4[0] + ws4[1] + ws4[2] + ws4[3];
}

__global__ void k_scan2(int* __restrict__ bsum, int nb) {
    __shared__ int s[256];
    int t = threadIdx.x;
    int v = (t < nb) ? bsum[t] : 0;
    s[t] = v;
    __syncthreads();
    for (int off = 1; off < 256; off <<= 1) {
        int a = (t >= off) ? s[t - off] : 0;
        __syncthreads();
        s[t] += a;
        __syncthreads();
    }
    if (t < nb) bsum[t] = s[t] - v;  // exclusive
}

__global__ void k_scan3(const int* __restrict__ counts, const int* __restrict__ boff,
                        int* __restrict__ rowptr) {
    __shared__ int s[256];
    int t = threadIdx.x;
    int i = blockIdx.x * 256 + t;
    int v = (i < NN) ? counts[i] : 0;
    s[t] = v;
    __syncthreads();
    for (int off = 1; off < 256; off <<= 1) {
        int a = (t >= off) ? s[t - off] : 0;
        __syncthreads();
        s[t] += a;
        __syncthreads();
    }
    int excl = s[t] - v + boff[blockIdx.x];
    if (i < NN) rowptr[i] = excl;
    if (i == NN - 1) rowptr[NN] = excl + v;  // == NE
}

__global__ void k_fill(const int* __restrict__ src, const int* __restrict__ tgt,
                       const int* __restrict__ rowptr, const int* __restrict__ rank,
                       int* __restrict__ csr) {
    int e = blockIdx.x * blockDim.x + threadIdx.x;
    if (e < NE) csr[rowptr[tgt[e]] + rank[e]] = src[e];
}

// ---------------- x -> bf16 cast ----------------

__global__ void k_xcast(const float* __restrict__ x, ushort* __restrict__ xb, int n8) {
    int i = blockIdx.x * 256 + threadIdx.x;
    if (i >= n8) return;
    float4 v0 = *(const float4*)&x[i * 8];
    float4 v1 = *(const float4*)&x[i * 8 + 4];
    ushort h[8] = {bf16_rne(v0.x), bf16_rne(v0.y), bf16_rne(v0.z), bf16_rne(v0.w),
                   bf16_rne(v1.x), bf16_rne(v1.y), bf16_rne(v1.z), bf16_rne(v1.w)};
    *(bf16x8*)&xb[i * 8] = *(bf16x8*)h;
}

// ---------------- CSR gather-mean aggregation (bf16 gather) ----------------

template <int D>
__global__ void k_aggb(const ushort* __restrict__ in,
                       const float* __restrict__ addp, int addStride,
                       float* __restrict__ out, int outStride,
                       const int* __restrict__ rowptr, const int* __restrict__ csr) {
    constexpr int LPR = D / 8;      // lanes per row: 8 (D=64) or 16 (D=128)
    constexpr int EPW = 64 / LPR;   // edge slots: 8 or 4
    int node = blockIdx.x * 4 + (threadIdx.x >> 6);
    int lane = threadIdx.x & 63;
    if (node >= NN) return;
    int sub = lane / LPR;
    int li  = lane % LPR;           // 8-elem group within row
    int r0 = rowptr[node], r1 = rowptr[node + 1];

    float a[8] = {0.f, 0.f, 0.f, 0.f, 0.f, 0.f, 0.f, 0.f};
    float b[8] = {0.f, 0.f, 0.f, 0.f, 0.f, 0.f, 0.f, 0.f};
    int e0 = r0 + sub;
    int e1 = e0 + EPW;
    int i0 = (e0 < r1) ? csr[e0] : 0;
    int i1 = (e1 < r1) ? csr[e1] : 0;
    while (e1 < r1) {
        int e0n = e0 + 2 * EPW, e1n = e1 + 2 * EPW;
        int i0n = (e0n < r1) ? csr[e0n] : 0;
        int i1n = (e1n < r1) ? csr[e1n] : 0;
        uint4 v0 = *(const uint4*)(in + (size_t)i0 * D + li * 8);
        uint4 v1 = *(const uint4*)(in + (size_t)i1 * D + li * 8);
        a[0] += lo_f(v0.x); a[1] += hi_f(v0.x); a[2] += lo_f(v0.y); a[3] += hi_f(v0.y);
        a[4] += lo_f(v0.z); a[5] += hi_f(v0.z); a[6] += lo_f(v0.w); a[7] += hi_f(v0.w);
        b[0] += lo_f(v1.x); b[1] += hi_f(v1.x); b[2] += lo_f(v1.y); b[3] += hi_f(v1.y);
        b[4] += lo_f(v1.z); b[5] += hi_f(v1.z); b[6] += lo_f(v1.w); b[7] += hi_f(v1.w);
        e0 = e0n; e1 = e1n; i0 = i0n; i1 = i1n;
    }
    if (e0 < r1) {
        uint4 v0 = *(const uint4*)(in + (size_t)i0 * D + li * 8);
        a[0] += lo_f(v0.x); a[1] += hi_f(v0.x); a[2] += lo_f(v0.y); a[3] += hi_f(v0.y);
        a[4] += lo_f(v0.z); a[5] += hi_f(v0.z); a[6] += lo_f(v0.w); a[7] += hi_f(v0.w);
    }
    #pragma unroll
    for (int j = 0; j < 8; j++) a[j] += b[j];
    #pragma unroll
    for (int off = LPR; off < 64; off <<= 1)
        #pragma unroll
        for (int j = 0; j < 8; j++) a[j] += __shfl_xor(a[j], off, 64);
    if (sub == 0) {
        float inv = 1.0f / fmaxf((float)(r1 - r0), 1.0f);
        #pragma unroll
        for (int j = 0; j < 8; j++) a[j] *= inv;
        if (addp) {
            float4 p0 = *(const float4*)&addp[(size_t)node * addStride + li * 8];
            float4 p1 = *(const float4*)&addp[(size_t)node * addStride + li * 8 + 4];
            a[0] += p0.x; a[1] += p0.y; a[2] += p0.z; a[3] += p0.w;
            a[4] += p1.x; a[5] += p1.y; a[6] += p1.z; a[7] += p1.w;
        }
        *(float4*)&out[(size_t)node * outStride + li * 8]     = make_float4(a[0], a[1], a[2], a[3]);
        *(float4*)&out[(size_t)node * outStride + li * 8 + 4] = make_float4(a[4], a[5], a[6], a[7]);
    }
}

// ---------------- weight pre-split: per-lane MFMA fragment layout ----------------
// frag[chunk][ct][lane][j] -> W[chunk*32 + (lane>>4)*8 + j][ct*16 + (lane&15)].

template <int K, int KA, int NCAT>
__global__ void k_wsplit(const float* __restrict__ W1, const float* __restrict__ W2,
                         ushort* __restrict__ hi, ushort* __restrict__ lo) {
    int id = blockIdx.x * 256 + threadIdx.x;
    if (id >= 128 * K) return;
    int col = id / K, k = id - col * K;
    float v;
    if constexpr (NCAT) {
        v = (col < 64) ? W1[(size_t)k * 64 + col] : W2[(size_t)k * 64 + (col - 64)];
    } else {
        v = (k < KA) ? W1[(size_t)k * 128 + col] : W2[(size_t)(k - KA) * 128 + col];
    }
    ushort h = bf16_rne(v);
    ushort l = bf16_rne(v - bf16_to_f(h));
    int chunk = k >> 5, kk = k & 31;
    int kg4 = kk >> 3, j = kk & 7;
    int ct = col >> 4, lr = col & 15;
    size_t dst = ((size_t)(chunk * 8 + ct) * 64 + kg4 * 16 + lr) * 8 + j;
    hi[dst] = h; lo[dst] = l;
}

// ---------------- MFMA GEMM (bf16x3 split = fp32 accuracy) ----------------
// Software-pipelined, barrier/LDS-free: W fragments double-buffered in regs;
// chunk c+1's 16 W-loads + A-load ISSUE BEFORE chunk c's MFMAs, so L2/L3
// latency hides under the 24-MFMA + convert block (loads stay in flight
// across compute). Static 2x unroll keeps all buffer indexing compile-time.
// Block: 256 thr = 4 waves x 16 rows. C = Ah@Wh + Ah@Wl + Al@Wh.
// MFMA layouts (m89): A[j]=A[lr][kg4*8+j], B[j]=B[kg4*8+j][lr], D[j]=C[kg4*4+j][lr].

template <int K, int KA, int NCAT, int RELU, int BFOUT>
__launch_bounds__(256, 3)
__global__ void k_mgemm(const float* __restrict__ inA, const float* __restrict__ inB,
                        const ushort* __restrict__ Whi, const ushort* __restrict__ Wlo,
                        const float* __restrict__ bias, float* __restrict__ out,
                        ushort* __restrict__ bfout) {
    constexpr int KB = K - KA;
    constexpr int NCH = K / 32;   // 4 or 8 (always even)

    int tid = threadIdx.x;
    int wave = tid >> 6, lane = tid & 63;
    int lr  = lane & 15;
    int kg4 = lane >> 4;
    int rbase = blockIdx.x * 64 + wave * 16;
    int row = min(rbase + lr, NN - 1);

    f32x4 acc[8];
    #pragma unroll
    for (int ct = 0; ct < 8; ct++) acc[ct] = (f32x4){0.f, 0.f, 0.f, 0.f};

    const ushort* baseH = Whi + (size_t)lane * 8;
    const ushort* baseL = Wlo + (size_t)lane * 8;

    auto loadA = [&](int chunk, float4& v0, float4& v1) {
        int kg2 = chunk * 32 + kg4 * 8;
        if constexpr (NCAT) {
            v0 = *(const float4*)&inA[(size_t)row * K + kg2];
            v1 = *(const float4*)&inA[(size_t)row * K + kg2 + 4];
        } else {
            if (kg2 < KA) v0 = *(const float4*)&inA[(size_t)row * KA + kg2];
            else          v0 = *(const float4*)&inB[(size_t)row * KB + (kg2 - KA)];
            if (kg2 + 4 < KA) v1 = *(const float4*)&inA[(size_t)row * KA + kg2 + 4];
            else              v1 = *(const float4*)&inB[(size_t)row * KB + (kg2 + 4 - KA)];
        }
    };

#define LOADW(c, WH, WL)                                          \
    {                                                             \
        const ushort* ph_ = baseH + (size_t)(c) * 4096;           \
        const ushort* pl_ = baseL + (size_t)(c) * 4096;           \
        _Pragma("unroll")                                         \
        for (int ct_ = 0; ct_ < 8; ct_++) {                       \
            WH[ct_] = *(const bf16x8*)(ph_ + ct_ * 512);          \
            WL[ct_] = *(const bf16x8*)(pl_ + ct_ * 512);          \
        }                                                         \
    }

#define CONVA(V0, V1, AH, AL)                                     \
    {                                                             \
        float av_[8] = {V0.x, V0.y, V0.z, V0.w, V1.x, V1.y, V1.z, V1.w}; \
        _Pragma("unroll")                                         \
        for (int j_ = 0; j_ < 8; j_++) {                          \
            ushort h_ = bf16_rne(av_[j_]);                        \
            ushort l_ = bf16_rne(av_[j_] - bf16_to_f(h_));        \
            AH[j_] = (short)h_;                                   \
            AL[j_] = (short)l_;                                   \
        }                                                         \
    }

#define MFMA3(AH, AL, WH, WL)                                     \
    {                                                             \
        _Pragma("unroll")                                         \
        for (int ct_ = 0; ct_ < 8; ct_++) {                       \
            acc[ct_] = __builtin_amdgcn_mfma_f32_16x16x32_bf16(AH, WH[ct_], acc[ct_], 0, 0, 0); \
            acc[ct_] = __builtin_amdgcn_mfma_f32_16x16x32_bf16(AH, WL[ct_], acc[ct_], 0, 0, 0); \
            acc[ct_] = __builtin_amdgcn_mfma_f32_16x16x32_bf16(AL, WH[ct_], acc[ct_], 0, 0, 0); \
        }                                                         \
    }

    bf16x8 whA[8], wlA[8], whB[8], wlB[8];
    float4 aC0, aC1, aN0, aN1;

    LOADW(0, whA, wlA);
    loadA(0, aC0, aC1);

    #pragma unroll
    for (int c = 0; c < NCH; c += 2) {
        // chunk c (buffer A). Issue chunk c+1 loads into buffer B FIRST.
        if (c + 1 < NCH) { LOADW(c + 1, whB, wlB); loadA(c + 1, aN0, aN1); }
        {
            bf16x8 ah, al;
            CONVA(aC0, aC1, ah, al);
            MFMA3(ah, al, whA, wlA);
        }
        // chunk c+1 (buffer B). Issue chunk c+2 loads into buffer A FIRST.
        if (c + 2 < NCH) { LOADW(c + 2, whA, wlA); loadA(c + 2, aC0, aC1); }
        if (c + 1 < NCH) {
            bf16x8 ah, al;
            CONVA(aN0, aN1, ah, al);
            MFMA3(ah, al, whB, wlB);
        }
    }
#undef LOADW
#undef CONVA
#undef MFMA3

    float bc[8];
    #pragma unroll
    for (int ct = 0; ct < 8; ct++) {
        int c = ct * 16 + lr;
        if constexpr (NCAT) bc[ct] = (c < 64) ? 0.f : bias[c - 64];
        else bc[ct] = bias[c];
    }
    #pragma unroll
    for (int j = 0; j < 4; j++) {
        int n = rbase + kg4 * 4 + j;
        if (n < NN) {
            float* orow = &out[(size_t)n * 128 + lr];
            #pragma unroll
            for (int ct = 0; ct < 8; ct++) {
                float v = acc[ct][j] + bc[ct];
                if (RELU) v = fmaxf(v, 0.f);
                orow[ct * 16] = v;
                if constexpr (BFOUT == 1) bfout[(size_t)n * 128 + ct * 16 + lr] = bf16_rne(v);
                if constexpr (BFOUT == 2) { if (ct < 4) bfout[(size_t)n * 64 + ct * 16 + lr] = bf16_rne(v); }
            }
        }
    }
}

// ---------------- decode ----------------

__global__ void k_decode(const int* __restrict__ eli, const float* __restrict__ z,
                         float* __restrict__ out) {
    int w = blockIdx.x * 4 + (threadIdx.x >> 6);
    int lane = threadIdx.x & 63;
    int sub = lane >> 4, li = lane & 15;
    int e0 = w * 8 + sub;
    int e1 = e0 + 4;
    float s0 = 0.f, s1 = 0.f;
    if (e0 < NL) {
        int a = eli[e0], b = eli[NL + e0];
        float4 va = *(const float4*)&z[(size_t)a * 64 + li * 4];
        float4 vb = *(const float4*)&z[(size_t)b * 64 + li * 4];
        s0 = va.x * vb.x + va.y * vb.y + va.z * vb.z + va.w * vb.w;
    }
    if (e1 < NL) {
        int a = eli[e1], b = eli[NL + e1];
        float4 va = *(const float4*)&z[(size_t)a * 64 + li * 4];
        float4 vb = *(const float4*)&z[(size_t)b * 64 + li * 4];
        s1 = va.x * vb.x + va.y * vb.y + va.z * vb.z + va.w * vb.w;
    }
    #pragma unroll
    for (int off = 1; off < 16; off <<= 1) {
        s0 += __shfl_xor(s0, off, 64);
        s1 += __shfl_xor(s1, off, 64);
    }
    if (li == 0) {
        if (e0 < NL) out[e0] = s0;
        if (e1 < NL) out[e1] = s1;
    }
}

// ---------------- launch ----------------

extern "C" void kernel_launch(void* const* d_in, const int* in_sizes, int n_in,
                              void* d_out, int out_size, void* d_ws, size_t ws_size,
                              hipStream_t stream) {
    const float* x   = (const float*)d_in[0];
    const int*   edge = (const int*)d_in[1];   // [2, NE]
    const int*   eli  = (const int*)d_in[2];   // [2, NL]
    const float* Wl1 = (const float*)d_in[3];
    const float* Wr1 = (const float*)d_in[4];
    const float* b1  = (const float*)d_in[5];
    const float* Wl2 = (const float*)d_in[6];
    const float* Wr2 = (const float*)d_in[7];
    const float* b2  = (const float*)d_in[8];
    const float* Wl3 = (const float*)d_in[9];
    const float* Wr3 = (const float*)d_in[10];
    const float* b3  = (const float*)d_in[11];
    float* out = (float*)d_out;

    char* w = (char*)d_ws;
    auto carve = [&](size_t bytes) {
        char* p = w;
        w += (bytes + 255) & ~(size_t)255;
        return p;
    };
    int*    rowptr = (int*)carve((NN + 1) * sizeof(int));
    int*    counts = (int*)carve(NN * sizeof(int));
    int*    rank   = (int*)carve(NE * sizeof(int));
    int*    csr    = (int*)carve(NE * sizeof(int));
    int*    bsum   = (int*)carve(256 * sizeof(int));
    float*  M      = (float*)carve((size_t)NN * 64 * sizeof(float));   // mean1, later z
    float*  A      = (float*)carve((size_t)NN * 128 * sizeof(float));  // h1
    float*  B      = (float*)carve((size_t)NN * 128 * sizeof(float));  // mean2, later pq
    float*  C      = (float*)carve((size_t)NN * 128 * sizeof(float));  // h2
    ushort* xb     = (ushort*)carve((size_t)NN * 64 * sizeof(ushort));  // bf16 x
    ushort* h1b    = (ushort*)carve((size_t)NN * 128 * sizeof(ushort)); // bf16 h1
    ushort* pb     = (ushort*)carve((size_t)NN * 64 * sizeof(ushort));  // bf16 p
    ushort* W1h    = (ushort*)carve(128 * 128 * sizeof(ushort));
    ushort* W1l    = (ushort*)carve(128 * 128 * sizeof(ushort));
    ushort* W2h    = (ushort*)carve(128 * 256 * sizeof(ushort));
    ushort* W2l    = (ushort*)carve(128 * 256 * sizeof(ushort));
    ushort* W3h    = (ushort*)carve(128 * 128 * sizeof(ushort));
    ushort* W3l    = (ushort*)carve(128 * 128 * sizeof(ushort));

    const int* src = edge;
    const int* tgt = edge + NE;

    // prep: weight pre-split (fragment layout) + x bf16 cast
    k_wsplit<128, 64, 0><<<64, 256, 0, stream>>>(Wl1, Wr1, W1h, W1l);
    k_wsplit<256, 128, 0><<<128, 256, 0, stream>>>(Wl2, Wr2, W2h, W2l);
    k_wsplit<128, 128, 1><<<64, 256, 0, stream>>>(Wl3, Wr3, W3h, W3l);
    k_xcast<<<(NN * 8 + 255) / 256, 256, 0, stream>>>(x, xb, NN * 8);

    // CSR build
    hipMemsetAsync(counts, 0, NN * sizeof(int), stream);
    k_count<<<(NE + 255) / 256, 256, 0, stream>>>(tgt, counts, rank);
    k_scan1<<<NB_SCAN, 256, 0, stream>>>(counts, bsum);
    k_scan2<<<1, 256, 0, stream>>>(bsum, NB_SCAN);
    k_scan3<<<NB_SCAN, 256, 0, stream>>>(counts, bsum, rowptr);
    k_fill<<<(NE + 255) / 256, 256, 0, stream>>>(src, tgt, rowptr, rank, csr);

    // layer 1: mean1 = mean(x); h1 = relu([mean1|x] @ [Wl1;Wr1] + b1)  (+h1 bf16 copy)
    k_aggb<64><<<(NN + 3) / 4, 256, 0, stream>>>(xb, nullptr, 0, M, 64, rowptr, csr);
    k_mgemm<128, 64, 0, 1, 1><<<(NN + 63) / 64, 256, 0, stream>>>(M, x, W1h, W1l, b1, A, h1b);

    // layer 2: mean2 = mean(h1); h2 = relu([mean2|h1] @ [Wl2;Wr2] + b2)
    k_aggb<128><<<(NN + 3) / 4, 256, 0, stream>>>(h1b, nullptr, 0, B, 128, rowptr, csr);
    k_mgemm<256, 128, 0, 1, 0><<<(NN + 63) / 64, 256, 0, stream>>>(B, A, W2h, W2l, b2, C, nullptr);

    // layer 3: pq = h2 @ [Wl3 | Wr3] (+p bf16 copy); z = scatter_mean(p) + q
    k_mgemm<128, 128, 1, 0, 2><<<(NN + 63) / 64, 256, 0, stream>>>(C, nullptr, W3h, W3l, b3, B, pb);
    k_aggb<64><<<(NN + 3) / 4, 256, 0, stream>>>(pb, B + 64, 128, M, 64, rowptr, csr);

    // decode: out[l] = dot(z[a], z[b])
    k_decode<<<(NL + 31) / 32, 256, 0, stream>>>(eli, M, out);
}